// Round 7
// baseline (333.906 us; speedup 1.0000x reference)
//
#include <hip/hip_runtime.h>

// TransformerLayer on MI355X (gfx950), bf16 MFMA pipeline, fp32 LN/softmax/accum.
// R13: ffn1/ffn2 move to 256-row tiles under the VERIFIED R8 2-phase sync
// (stage-next -> ds_read+MFMA -> one __syncthreads per K-step; no inline
// waitcnts, no sched_barriers). m230: 256-tile+2ph = 682 TF vs 128-tile+2ph =
// 622 -- tile size pays without the fragile 8-phase schedule. Grids sized for
// perfect 256-block fill: ffn1 256x256 (16x16), ffn2 256x128 z=2 (16x8x2, same
// full-M fp32 partial as R12). qkv stays on the measured 128x128 R8 body.
// Everything else = R12 (best verified: 326.7us).

typedef unsigned short u16;
typedef unsigned int   u32;
typedef __bf16 bf16x8 __attribute__((ext_vector_type(8)));
typedef float  f32x4  __attribute__((ext_vector_type(4)));

#define NEG_INF (-__builtin_inff())

#if __has_builtin(__builtin_amdgcn_exp2f)
#define EXP2F(x) __builtin_amdgcn_exp2f(x)
#else
#define EXP2F(x) exp2f(x)
#endif

// pack: result = lo16:=a.hi16, hi16:=b.hi16 (trunc bf16 pair)
__device__ __forceinline__ u32 pack_bf16_trunc(float a, float b) {
#if __has_builtin(__builtin_amdgcn_perm)
  return __builtin_amdgcn_perm(__float_as_uint(b), __float_as_uint(a), 0x07060302u);
#else
  return (__float_as_uint(a) >> 16) | (__float_as_uint(b) & 0xFFFF0000u);
#endif
}

// fp32 -> bf16 RNE (finite inputs only)
__device__ __forceinline__ u16 f2b(float f) {
  u32 u = __float_as_uint(f);
  u = (u + 0x7fffu + ((u >> 16) & 1u)) >> 16;
  return (u16)u;
}

// async global->LDS, 16B per lane. LDS dest must be wave-uniform base + lane*16.
__device__ __forceinline__ void gload16(const void* g, void* l) {
  __builtin_amdgcn_global_load_lds(
      (const __attribute__((address_space(1))) u32*)g,
      (__attribute__((address_space(3))) u32*)l, 16, 0, 0);
}

__device__ __forceinline__ bf16x8 ld16(const u16* p) { return *(const bf16x8*)p; }

// ---------------------------------------------------------------------------
// ALL weight transposes (fp32 -> bf16, [R][C] -> [C][R]) in ONE flat launch.
__global__ __launch_bounds__(256)
void transpose_all_k(const float* __restrict__ W1, const float* __restrict__ W2,
                     const float* __restrict__ Wq, const float* __restrict__ Wk,
                     const float* __restrict__ Wv,
                     u16* __restrict__ W1t, u16* __restrict__ W2t,
                     u16* __restrict__ Wqkv_t) {
  __shared__ float tile[64][65];
  int id = blockIdx.x;
  const float* in; u16* out; int R, C, r0, c0;
  if (id < 1024) {
    in = W1; out = W1t; R = 1024; C = 4096;
    r0 = (id & 15) * 64; c0 = (id >> 4) * 64;
  } else if (id < 2048) {
    id -= 1024;
    in = W2; out = W2t; R = 4096; C = 1024;
    r0 = (id >> 4) * 64; c0 = (id & 15) * 64;
  } else {
    id -= 2048;                       // 0..767: 48 head-matrices x 16 row-chunks
    int z = id >> 4, which = z >> 4, sub = z & 15;
    const float* base = which == 0 ? Wq : (which == 1 ? Wk : Wv);
    in = base + (size_t)sub * 1024 * 64;
    out = Wqkv_t + (size_t)which * 1024 * 1024 + (size_t)sub * 64 * 1024;
    R = 1024; C = 64;
    r0 = (id & 15) * 64; c0 = 0;
  }
  int tr = threadIdx.x >> 6, tc = threadIdx.x & 63;
#pragma unroll
  for (int i = 0; i < 16; i++) {
    int r = i * 4 + tr;
    tile[r][tc] = in[(size_t)(r0 + r) * C + c0 + tc];
  }
  __syncthreads();
#pragma unroll
  for (int i = 0; i < 16; i++) {
    int c = i * 4 + tr;
    out[(size_t)(c0 + c) * R + r0 + tc] = f2b(tile[tc][c]);
  }
}

// ---------------------------------------------------------------------------
// bf16 transpose for V: vin [bh][2048][64] -> vt [bh][64][2048]
__global__ __launch_bounds__(256)
void vtrans_k(const u16* __restrict__ vin, u16* __restrict__ vt) {
  __shared__ __align__(16) u16 tile[64][72];
  int s0 = blockIdx.x * 64, bh = blockIdx.y;
  const u16* ip = vin + (size_t)bh * 2048 * 64;
  u16* op = vt + (size_t)bh * 64 * 2048;
  int t = threadIdx.x;
#pragma unroll
  for (int i = 0; i < 2; i++) {
    int idx = i * 256 + t, r = idx >> 3, c = idx & 7;
    *(uint4*)&tile[r][c * 8] = *(const uint4*)(ip + (size_t)(s0 + r) * 64 + c * 8);
  }
  __syncthreads();
#pragma unroll
  for (int i = 0; i < 16; i++) {
    int d = i * 4 + (t >> 6), s = t & 63;
    op[(size_t)d * 2048 + s0 + s] = tile[s][d];
  }
}

// ---------------------------------------------------------------------------
// LayerNorm over rows of 1024.
__global__ __launch_bounds__(256)
void ln_k(const float* __restrict__ in, const float* __restrict__ in2,
          const float* __restrict__ w, const float* __restrict__ b,
          float* __restrict__ outf, u16* __restrict__ outb) {
  int row = blockIdx.x, t = threadIdx.x;
  const float4* ip = (const float4*)(in + (size_t)row * 1024);
  float4 x = ip[t];
  if (in2) {
    const float4* ip2 = (const float4*)(in2 + (size_t)row * 1024);
    float4 o = ip2[t];
    x.x += o.x; x.y += o.y; x.z += o.z; x.w += o.w;
  }
  float s = x.x + x.y + x.z + x.w;
  float q = x.x * x.x + x.y * x.y + x.z * x.z + x.w * x.w;
#pragma unroll
  for (int m = 32; m; m >>= 1) { s += __shfl_xor(s, m); q += __shfl_xor(q, m); }
  __shared__ float rs[4], rq[4];
  if ((t & 63) == 0) { rs[t >> 6] = s; rq[t >> 6] = q; }
  __syncthreads();
  s = rs[0] + rs[1] + rs[2] + rs[3];
  q = rq[0] + rq[1] + rq[2] + rq[3];
  float mean = s * (1.f / 1024.f);
  float var  = q * (1.f / 1024.f) - mean * mean;
  float rstd = rsqrtf(var + 1e-5f);
  float4 wv = ((const float4*)w)[t];
  float4 bv = ((const float4*)b)[t];
  float4 y;
  y.x = (x.x - mean) * rstd * wv.x + bv.x;
  y.y = (x.y - mean) * rstd * wv.y + bv.y;
  y.z = (x.z - mean) * rstd * wv.z + bv.z;
  y.w = (x.w - mean) * rstd * wv.w + bv.w;
  if (outf) ((float4*)(outf + (size_t)row * 1024))[t] = y;
  ushort4 ub;
  ub.x = f2b(y.x); ub.y = f2b(y.y); ub.z = f2b(y.z); ub.w = f2b(y.w);
  ((ushort4*)(outb + (size_t)row * 1024))[t] = ub;
}

// ---------------------------------------------------------------------------
#define EPI_QKV  0
#define EPI_RELU 1
#define EPI_RES  2

// 0.125 * log2(e): folds the 1/sqrt(64) score scale AND the exp->exp2
// conversion into the Q projection (attention uses exp2 directly).
#define QSCALE 0.18033688011112042f

// ---------------------------------------------------------------------------
// 128x128 tile bf16 GEMM body, BK=64, 256 threads (R8, verified) -- qkv only.
__device__ __forceinline__
void gemm_qkv_body(const u16* __restrict__ A, const u16* __restrict__ Bt,
                   int K, int lda, int ldbt,
                   const float* __restrict__ bias0, const float* __restrict__ bias1,
                   const float* __restrict__ bias2, u16* __restrict__ outb) {
  __shared__ __align__(16) u16 As[2][128 * 64];
  __shared__ __align__(16) u16 Bs[2][128 * 64];
  int t = threadIdx.x;
  int wave = t >> 6, lane = t & 63, quad = lane >> 4, l16 = lane & 15;
  int x7 = l16 & 7;
  int wm = (wave >> 1) * 64, wn = (wave & 1) * 64;
  int bm = blockIdx.x * 128, bn = blockIdx.y * 128;

  const u16* Agl[4];
  const u16* Bgl[4];
#pragma unroll
  for (int i = 0; i < 4; i++) {
    int idx = i * 256 + t, r = idx >> 3, c = (idx & 7) ^ (r & 7);
    Agl[i] = A + (size_t)(bm + r) * lda + c * 8;
    Bgl[i] = Bt + (size_t)(bn + r) * ldbt + c * 8;
  }

  f32x4 acc[4][4] = {};

#pragma unroll
  for (int i = 0; i < 4; i++) {
    gload16(Agl[i], (u16*)As[0] + t * 8 + i * 2048);
    gload16(Bgl[i], (u16*)Bs[0] + t * 8 + i * 2048);
  }
  __syncthreads();

  int nk = K >> 6;
  for (int kt = 0; kt < nk; kt++) {
    const u16* Ac = As[kt & 1];
    const u16* Bc = Bs[kt & 1];
    if (kt + 1 < nk) {
      int k1 = (kt + 1) << 6;
      u16* An = (u16*)As[(kt + 1) & 1] + t * 8;
      u16* Bn = (u16*)Bs[(kt + 1) & 1] + t * 8;
#pragma unroll
      for (int i = 0; i < 4; i++) {
        gload16(Agl[i] + k1, An + i * 2048);
        gload16(Bgl[i] + k1, Bn + i * 2048);
      }
    }
#pragma unroll
    for (int kc = 0; kc < 2; kc++) {
      bf16x8 af[4], bfr[4];
#pragma unroll
      for (int i = 0; i < 4; i++) {
        int r = wm + i * 16 + l16;
        af[i] = *(const bf16x8*)(Ac + r * 64 + (((kc * 4 + quad) ^ x7) * 8));
      }
#pragma unroll
      for (int j = 0; j < 4; j++) {
        int r = wn + j * 16 + l16;
        bfr[j] = *(const bf16x8*)(Bc + r * 64 + (((kc * 4 + quad) ^ x7) * 8));
      }
#pragma unroll
      for (int i = 0; i < 4; i++)
#pragma unroll
        for (int j = 0; j < 4; j++)
          acc[i][j] = __builtin_amdgcn_mfma_f32_16x16x32_bf16(af[i], bfr[j],
                                                              acc[i][j], 0, 0, 0);
    }
    __syncthreads();
  }

#pragma unroll
  for (int i = 0; i < 4; i++) {
#pragma unroll
    for (int j = 0; j < 4; j++) {
      int c = bn + wn + j * 16 + l16;
#pragma unroll
      for (int rr = 0; rr < 4; rr++) {
        int r = bm + wm + i * 16 + quad * 4 + rr;
        float v = acc[i][j][rr];
        int which = c >> 10, h = (c >> 6) & 15, d = c & 63;
        const float* bp = which == 0 ? bias0 : (which == 1 ? bias1 : bias2);
        v += bp[h * 64 + d];
        if (which == 0) v *= QSCALE;  // prescale Q for base-2 softmax
        int bb = r >> 11, ss = r & 2047;
        outb[((size_t)(which * 32 + bb * 16 + h) * 2048 + ss) * 64 + d] = f2b(v);
      }
    }
  }
}

__global__ __launch_bounds__(256)
void qkv_gemm(const u16* A, const u16* Bt, int K, int lda, int ldbt,
              const float* b0, const float* b1, const float* b2,
              u16* outb) {
  gemm_qkv_body(A, Bt, K, lda, ldbt, b0, b1, b2, outb);
}

// ---------------------------------------------------------------------------
// 256xBN tile (BN=256 or 128), BK=64, 512 threads (8 waves), R8 2-phase sync:
// stage next tile -> ds_read cur + MFMA -> ONE __syncthreads per K-step.
// Wave layout: MW x NW grid of waves, MW = 8/(BN/64), per-wave (256/MW) x 64.
// Same chunk-XOR swizzle as the 128-tile body (bank-conflict-free, verified).
template <int EPI, int BN>
__device__ __forceinline__
void gemm256_body(const u16* __restrict__ A, const u16* __restrict__ Bt,
                  int K, int lda, int ldbt,
                  const float* __restrict__ bias0, const float* __restrict__ res,
                  int ldout, u16* __restrict__ outb, float* __restrict__ outf,
                  float* __restrict__ outp) {
  constexpr int NW = BN / 64;        // waves along N (4 or 2) = B stage units
  constexpr int MW = 8 / NW;         // waves along M (2 or 4)
  constexpr int MR = (256 / MW) / 16; // acc M-frags per wave (8 or 4)
  __shared__ __align__(16) u16 As[2][256 * 64];
  __shared__ __align__(16) u16 Bs[2][BN * 64];
  int t = threadIdx.x;                // 0..511
  int wave = t >> 6, lane = t & 63, quad = lane >> 4, l16 = lane & 15;
  int x7 = l16 & 7;
  int wr0 = (wave / NW) * (256 / MW);
  int wc0 = (wave % NW) * 64;
  int bm = blockIdx.x * 256, bn = blockIdx.y * BN;
  int zoff = blockIdx.z * K;

  const u16* Ag[4];
  const u16* Bg[NW];
#pragma unroll
  for (int i = 0; i < 4; i++) {
    int idx = i * 512 + t, r = idx >> 3, c = (idx & 7) ^ (r & 7);
    Ag[i] = A + (size_t)(bm + r) * lda + zoff + c * 8;
  }
#pragma unroll
  for (int i = 0; i < NW; i++) {
    int idx = i * 512 + t, r = idx >> 3, c = (idx & 7) ^ (r & 7);
    Bg[i] = Bt + (size_t)(bn + r) * ldbt + zoff + c * 8;
  }

  f32x4 acc[MR][4] = {};

  // prologue: stage tile 0 into buffer 0
#pragma unroll
  for (int i = 0; i < 4; i++) gload16(Ag[i], (u16*)As[0] + t * 8 + i * 4096);
#pragma unroll
  for (int i = 0; i < NW; i++) gload16(Bg[i], (u16*)Bs[0] + t * 8 + i * 4096);
  __syncthreads();

  int nk = K >> 6;
  for (int kt = 0; kt < nk; kt++) {
    const u16* Ac = As[kt & 1];
    const u16* Bc = Bs[kt & 1];
    if (kt + 1 < nk) {
      int k1 = (kt + 1) << 6;
      u16* An = (u16*)As[(kt + 1) & 1] + t * 8;
      u16* Bn = (u16*)Bs[(kt + 1) & 1] + t * 8;
#pragma unroll
      for (int i = 0; i < 4; i++) gload16(Ag[i] + k1, An + i * 4096);
#pragma unroll
      for (int i = 0; i < NW; i++) gload16(Bg[i] + k1, Bn + i * 4096);
    }
#pragma unroll
    for (int kc = 0; kc < 2; kc++) {
      bf16x8 af[MR], bfr[4];
#pragma unroll
      for (int i = 0; i < MR; i++) {
        int r = wr0 + i * 16 + l16;
        af[i] = *(const bf16x8*)(Ac + r * 64 + (((kc * 4 + quad) ^ x7) * 8));
      }
#pragma unroll
      for (int j = 0; j < 4; j++) {
        int r = wc0 + j * 16 + l16;
        bfr[j] = *(const bf16x8*)(Bc + r * 64 + (((kc * 4 + quad) ^ x7) * 8));
      }
#pragma unroll
      for (int i = 0; i < MR; i++)
#pragma unroll
        for (int j = 0; j < 4; j++)
          acc[i][j] = __builtin_amdgcn_mfma_f32_16x16x32_bf16(af[i], bfr[j],
                                                              acc[i][j], 0, 0, 0);
    }
    __syncthreads();
  }

  // epilogue: wave writes its (256/MW) x 64 region
#pragma unroll
  for (int i = 0; i < MR; i++) {
#pragma unroll
    for (int j = 0; j < 4; j++) {
      int c = bn + wc0 + j * 16 + l16;
#pragma unroll
      for (int rr = 0; rr < 4; rr++) {
        int r = bm + wr0 + i * 16 + quad * 4 + rr;
        float v = acc[i][j][rr];
        if (EPI == EPI_RELU) {
          v += bias0[c];
          v = v > 0.f ? v : 0.f;
          outb[(size_t)r * ldout + c] = f2b(v);
        } else {
          if (blockIdx.z == 0) {
            v += bias0[c] + res[(size_t)r * ldout + c];
            outf[(size_t)r * ldout + c] = v;
          } else {
            outp[(size_t)r * ldout + c] = v;  // full-M fp32 partial (z=1)
          }
        }
      }
    }
  }
}

__global__ __launch_bounds__(512, 2)
void ffn1_gemm(const u16* A, const u16* Bt, int K, int lda, int ldbt,
               const float* b0, int ldout, u16* outb) {
  gemm256_body<EPI_RELU, 256>(A, Bt, K, lda, ldbt, b0, nullptr, ldout, outb,
                              nullptr, nullptr);
}

__global__ __launch_bounds__(512, 2)
void ffn2_gemm(const u16* A, const u16* Bt, int K, int lda, int ldbt,
               const float* b0, const float* res, int ldout,
               float* outf, float* outp) {
  gemm256_body<EPI_RES, 128>(A, Bt, K, lda, ldbt, b0, res, ldout,
                             nullptr, outf, outp);
}

// out[i] += part[i]  (fp32, float4)
__global__ __launch_bounds__(256)
void reduce_k(float* __restrict__ out, const float* __restrict__ part) {
  int i = blockIdx.x * 256 + threadIdx.x;
  float4 a = ((const float4*)part)[i];
  float4 b = ((float4*)out)[i];
  b.x += a.x; b.y += a.y; b.z += a.z; b.w += a.w;
  ((float4*)out)[i] = b;
}

// ---------------------------------------------------------------------------
// Flash attention v5, causal. Grid (16, 32), 512 threads (8 waves). [verified]
__global__ __launch_bounds__(512, 6)
void attn_k(const u16* __restrict__ qkv, const u16* __restrict__ vt,
            float* __restrict__ o) {
  int bh = blockIdx.y, b = bh >> 4, h = bh & 15;
  int Qt = b ? (15 - (int)blockIdx.x) : (int)blockIdx.x;  // causal balance
  int t = threadIdx.x;
  int wave = t >> 6, lane = t & 63, quad = lane >> 4, l16 = lane & 15;
  int x7 = l16 & 7;
  int q0 = Qt * 128 + wave * 16;

  const u16* qg = qkv + (size_t)bh * (2048 * 64);
  const u16* kg = qkv + (size_t)(32 + bh) * (2048 * 64);
  const u16* vg = vt + (size_t)bh * (64 * 2048);  // [dh][s]

  __shared__ __align__(16) u16 Ks[2][64 * 64];
  __shared__ __align__(16) u16 Vs[2][64 * 64];
  __shared__ __align__(16) u16 Ps[8][16 * 64 + 32];  // +64B aux per wave
  u16* Pw = Ps[wave];
  float* auxf = (float*)(Pw + 1024);

  int sr = t >> 3, sc_ = (t & 7) ^ (sr & 7);

  gload16(kg + (size_t)sr * 64 + sc_ * 8, Ks[0] + t * 8);
  gload16(vg + (size_t)sr * 2048 + sc_ * 8, Vs[0] + t * 8);

  bf16x8 qf0 = ld16(qg + (size_t)(q0 + l16) * 64 + quad * 8);
  bf16x8 qf1 = ld16(qg + (size_t)(q0 + l16) * 64 + 32 + quad * 8);

  f32x4 oacc[4] = {};
  float mo = NEG_INF, ll = 0.f;
  int kmax_w = q0 >> 6;
  int klast = 2 * Qt + 1;

  __syncthreads();

  for (int kt = 0; kt <= klast; kt++) {
    const u16* ks = Ks[kt & 1];
    const u16* vs = Vs[kt & 1];
    if (kt < klast) {
      gload16(kg + (size_t)((kt + 1) * 64 + sr) * 64 + sc_ * 8, Ks[(kt + 1) & 1] + t * 8);
      gload16(vg + (size_t)sr * 2048 + (kt + 1) * 64 + sc_ * 8, Vs[(kt + 1) & 1] + t * 8);
    }
    if (kt <= kmax_w) {
      // ---- S^T: A = K rows (m = kv), B = Q rows (n = q) ----
      f32x4 sc[4];
#pragma unroll
      for (int g = 0; g < 4; g++) {
        const u16* kr = ks + (g * 16 + l16) * 64;
        bf16x8 kf0 = *(const bf16x8*)(kr + ((quad ^ x7) * 8));
        bf16x8 kf1 = *(const bf16x8*)(kr + (((4 + quad) ^ x7) * 8));
        f32x4 s = {};
        s = __builtin_amdgcn_mfma_f32_16x16x32_bf16(kf0, qf0, s, 0, 0, 0);
        s = __builtin_amdgcn_mfma_f32_16x16x32_bf16(kf1, qf1, s, 0, 0, 0);
        sc[g] = s;
      }

      if (kt == kmax_w) {  // diagonal tile: mask kv > q
#pragma unroll
        for (int g = 0; g < 4; g++) {
          int kvb = kt * 64 + g * 16 + quad * 4;
#pragma unroll
          for (int rr = 0; rr < 4; rr++)
            if (kvb + rr > q0 + l16) sc[g][rr] = NEG_INF;
        }
      }

      // ---- online softmax, row = q = l16 ----
      float mx = sc[0][0];
#pragma unroll
      for (int g = 0; g < 4; g++)
#pragma unroll
        for (int rr = 0; rr < 4; rr++) mx = fmaxf(mx, sc[g][rr]);
      mx = fmaxf(mx, __shfl_xor(mx, 16));
      mx = fmaxf(mx, __shfl_xor(mx, 32));
      float mnew = fmaxf(mo, mx);
      float al = EXP2F(mo - mnew);
      mo = mnew;

      float sum = 0.f;
#pragma unroll
      for (int g = 0; g < 4; g++) {
        float p0 = EXP2F(sc[g][0] - mnew);
        float p1 = EXP2F(sc[g][1] - mnew);
        float p2 = EXP2F(sc[g][2] - mnew);
        float p3 = EXP2F(sc[g][3] - mnew);
        sum += (p0 + p1) + (p2 + p3);
        u32 lo = pack_bf16_trunc(p0, p1);
        u32 hi = pack_bf16_trunc(p2, p3);
        int slot = (2 * g + (quad >> 1)) ^ x7;
        *(uint2*)(Pw + l16 * 64 + slot * 8 + (quad & 1) * 4) = make_uint2(lo, hi);
      }
      sum += __shfl_xor(sum, 16);
      sum += __shfl_xor(sum, 32);
      ll = ll * al + sum;

      // rescale O: alpha indexed by q=l16 -> broadcast via per-wave LDS aux
      if (lane < 16) auxf[lane] = al;
      f32x4 av = *(const f32x4*)(auxf + quad * 4);
#pragma unroll
      for (int g = 0; g < 4; g++)
#pragma unroll
        for (int rr = 0; rr < 4; rr++) oacc[g][rr] *= av[rr];

      // ---- O += P(A) x V^T(B) ----
      bf16x8 pf0 = *(const bf16x8*)(Pw + l16 * 64 + ((quad ^ x7) * 8));
      bf16x8 pf1 = *(const bf16x8*)(Pw + l16 * 64 + (((4 + quad) ^ x7) * 8));
#pragma unroll
      for (int g = 0; g < 4; g++) {
        const u16* vr = vs + (g * 16 + l16) * 64;
        bf16x8 vf0 = *(const bf16x8*)(vr + ((quad ^ x7) * 8));
        bf16x8 vf1 = *(const bf16x8*)(vr + (((4 + quad) ^ x7) * 8));
        oacc[g] = __builtin_amdgcn_mfma_f32_16x16x32_bf16(pf0, vf0, oacc[g], 0, 0, 0);
        oacc[g] = __builtin_amdgcn_mfma_f32_16x16x32_bf16(pf1, vf1, oacc[g], 0, 0, 0);
      }
    }
    __syncthreads();
  }

  // epilogue: O row = m = quad*4+rr, col = dh = g*16+l16; l indexed by l16
  if (lane < 16) auxf[lane] = ll;
  f32x4 lv = *(const f32x4*)(auxf + quad * 4);
  float rinv[4];
#pragma unroll
  for (int rr = 0; rr < 4; rr++) rinv[rr] = 1.f / lv[rr];
  float* op = o + ((size_t)b * 2048 + q0) * 1024 + h * 64;
#pragma unroll
  for (int g = 0; g < 4; g++)
#pragma unroll
    for (int rr = 0; rr < 4; rr++)
      op[(size_t)(quad * 4 + rr) * 1024 + g * 16 + l16] = oacc[g][rr] * rinv[rr];
}

// ---------------------------------------------------------------------------
extern "C" void kernel_launch(void* const* d_in, const int* in_sizes, int n_in,
                              void* d_out, int out_size, void* d_ws, size_t ws_size,
                              hipStream_t stream) {
  const float* emb  = (const float*)d_in[0];
  const float* Wq   = (const float*)d_in[1];
  const float* bq   = (const float*)d_in[2];
  const float* Wk   = (const float*)d_in[3];
  const float* bk   = (const float*)d_in[4];
  const float* Wv   = (const float*)d_in[5];
  const float* bv   = (const float*)d_in[6];
  const float* ln1w = (const float*)d_in[7];
  const float* ln1b = (const float*)d_in[8];
  const float* ln2w = (const float*)d_in[9];
  const float* ln2b = (const float*)d_in[10];
  const float* W1   = (const float*)d_in[11];
  const float* b1   = (const float*)d_in[12];
  const float* W2   = (const float*)d_in[13];
  const float* b2   = (const float*)d_in[14];
  float* out = (float*)d_out;

  char* p = (char*)d_ws;
  u16*   Wqkv_t = (u16*)p;   p += (size_t)3072 * 1024 * 2;
  u16*   W1t    = (u16*)p;   p += (size_t)4096 * 1024 * 2;
  u16*   W2t    = (u16*)p;   p += (size_t)1024 * 4096 * 2;
  float* x      = (float*)p; p += (size_t)4096 * 1024 * 4;
  u16*   xb     = (u16*)p;   p += (size_t)4096 * 1024 * 2;
  u16*   qkvb   = (u16*)p;   p += (size_t)3 * 32 * 2048 * 64 * 2;  // 25.2 MB
  float* ob     = (float*)p; p += (size_t)4096 * 1024 * 4;         // 16.8 MB
  float* y      = (float*)p; p += (size_t)4096 * 1024 * 4;
  u16*   yb     = (u16*)p;   p += (size_t)4096 * 1024 * 2;
  u16*   hb     = (u16*)qkvb; // alias: qkvb+ob (42 MB) dead before FFN1 writes hb (33.6 MB)
  u16*   vT     = (u16*)y;    // alias: vT (8.4 MB) dead before ln2 writes y
  float* part   = x;          // alias: x (16.8 MB fp32) dead before FFN2 z=1 partial
  if (ws_size < (size_t)(p - (char*)d_ws)) return;

  // all weight transposes in one launch: 1024 (W1) + 1024 (W2) + 768 (QKV)
  transpose_all_k<<<dim3(2816), 256, 0, stream>>>(
      W1, W2, Wq, Wk, Wv, W1t, W2t, Wqkv_t);

  ln_k<<<dim3(4096), 256, 0, stream>>>(emb, nullptr, ln1w, ln1b, x, xb);

  qkv_gemm<<<dim3(32, 24, 1), 256, 0, stream>>>(
      xb, Wqkv_t, 1024, 1024, 1024, bq, bk, bv, qkvb);

  vtrans_k<<<dim3(32, 32), 256, 0, stream>>>(qkvb + (size_t)64 * 2048 * 64, vT);

  attn_k<<<dim3(16, 32), 512, 0, stream>>>(qkvb, vT, ob);

  ln_k<<<dim3(4096), 256, 0, stream>>>(x, ob, ln2w, ln2b, y, yb);

  // FFN1: 256x256 tiles, grid 16x16 = 256 blocks = 1/CU perfect fill
  ffn1_gemm<<<dim3(16, 16, 1), 512, 0, stream>>>(
      yb, W1t, 1024, 1024, 1024, b1, 4096, hb);

  // FFN2: 256x128 tiles, split-K=2, grid 16x8x2 = 256 blocks perfect fill
  ffn2_gemm<<<dim3(16, 8, 2), 512, 0, stream>>>(
      hb, W2t, 2048, 4096, 4096, b2, y, 1024, out, part);

  reduce_k<<<dim3(4096), 256, 0, stream>>>(out, part);
}

// Round 8
// 330.224 us; speedup vs baseline: 1.0112x; 1.0112x over previous
//
#include <hip/hip_runtime.h>

// TransformerLayer on MI355X (gfx950), bf16 MFMA pipeline, fp32 LN/softmax/accum.
// R14: GEMMs = exact R12 revert (verified best 326.7us; R13's 256-tile @ 2ph
// regressed: 1 block/CU loses the cross-block barrier overlap that 128sq @
// 2 blocks/CU gets -- m114). New: attn_k gains the two attn-measured catalog
// techniques: T5 setprio(1) around QK^T/PV MFMA clusters (m191: +4-7% attn;
// NOT applied to GEMMs where it hurts, m190) and T13 defer-max with THR=8
// (m214v23: +5%; exact math -- same reference max scales P, ll, O; P<=2^8 in
// base-2 domain, fp32 accum).

typedef unsigned short u16;
typedef unsigned int   u32;
typedef __bf16 bf16x8 __attribute__((ext_vector_type(8)));
typedef float  f32x4  __attribute__((ext_vector_type(4)));

#define NEG_INF (-__builtin_inff())

#if __has_builtin(__builtin_amdgcn_exp2f)
#define EXP2F(x) __builtin_amdgcn_exp2f(x)
#else
#define EXP2F(x) exp2f(x)
#endif

// pack: result = lo16:=a.hi16, hi16:=b.hi16 (trunc bf16 pair)
__device__ __forceinline__ u32 pack_bf16_trunc(float a, float b) {
#if __has_builtin(__builtin_amdgcn_perm)
  return __builtin_amdgcn_perm(__float_as_uint(b), __float_as_uint(a), 0x07060302u);
#else
  return (__float_as_uint(a) >> 16) | (__float_as_uint(b) & 0xFFFF0000u);
#endif
}

// fp32 -> bf16 RNE (finite inputs only)
__device__ __forceinline__ u16 f2b(float f) {
  u32 u = __float_as_uint(f);
  u = (u + 0x7fffu + ((u >> 16) & 1u)) >> 16;
  return (u16)u;
}

// async global->LDS, 16B per lane. LDS dest must be wave-uniform base + lane*16.
__device__ __forceinline__ void gload16(const void* g, void* l) {
  __builtin_amdgcn_global_load_lds(
      (const __attribute__((address_space(1))) u32*)g,
      (__attribute__((address_space(3))) u32*)l, 16, 0, 0);
}

__device__ __forceinline__ bf16x8 ld16(const u16* p) { return *(const bf16x8*)p; }

// ---------------------------------------------------------------------------
// ALL weight transposes (fp32 -> bf16, [R][C] -> [C][R]) in ONE flat launch.
__global__ __launch_bounds__(256)
void transpose_all_k(const float* __restrict__ W1, const float* __restrict__ W2,
                     const float* __restrict__ Wq, const float* __restrict__ Wk,
                     const float* __restrict__ Wv,
                     u16* __restrict__ W1t, u16* __restrict__ W2t,
                     u16* __restrict__ Wqkv_t) {
  __shared__ float tile[64][65];
  int id = blockIdx.x;
  const float* in; u16* out; int R, C, r0, c0;
  if (id < 1024) {
    in = W1; out = W1t; R = 1024; C = 4096;
    r0 = (id & 15) * 64; c0 = (id >> 4) * 64;
  } else if (id < 2048) {
    id -= 1024;
    in = W2; out = W2t; R = 4096; C = 1024;
    r0 = (id >> 4) * 64; c0 = (id & 15) * 64;
  } else {
    id -= 2048;                       // 0..767: 48 head-matrices x 16 row-chunks
    int z = id >> 4, which = z >> 4, sub = z & 15;
    const float* base = which == 0 ? Wq : (which == 1 ? Wk : Wv);
    in = base + (size_t)sub * 1024 * 64;
    out = Wqkv_t + (size_t)which * 1024 * 1024 + (size_t)sub * 64 * 1024;
    R = 1024; C = 64;
    r0 = (id & 15) * 64; c0 = 0;
  }
  int tr = threadIdx.x >> 6, tc = threadIdx.x & 63;
#pragma unroll
  for (int i = 0; i < 16; i++) {
    int r = i * 4 + tr;
    tile[r][tc] = in[(size_t)(r0 + r) * C + c0 + tc];
  }
  __syncthreads();
#pragma unroll
  for (int i = 0; i < 16; i++) {
    int c = i * 4 + tr;
    out[(size_t)(c0 + c) * R + r0 + tc] = f2b(tile[tc][c]);
  }
}

// ---------------------------------------------------------------------------
// bf16 transpose for V: vin [bh][2048][64] -> vt [bh][64][2048]
__global__ __launch_bounds__(256)
void vtrans_k(const u16* __restrict__ vin, u16* __restrict__ vt) {
  __shared__ __align__(16) u16 tile[64][72];
  int s0 = blockIdx.x * 64, bh = blockIdx.y;
  const u16* ip = vin + (size_t)bh * 2048 * 64;
  u16* op = vt + (size_t)bh * 64 * 2048;
  int t = threadIdx.x;
#pragma unroll
  for (int i = 0; i < 2; i++) {
    int idx = i * 256 + t, r = idx >> 3, c = idx & 7;
    *(uint4*)&tile[r][c * 8] = *(const uint4*)(ip + (size_t)(s0 + r) * 64 + c * 8);
  }
  __syncthreads();
#pragma unroll
  for (int i = 0; i < 16; i++) {
    int d = i * 4 + (t >> 6), s = t & 63;
    op[(size_t)d * 2048 + s0 + s] = tile[s][d];
  }
}

// ---------------------------------------------------------------------------
// LayerNorm over rows of 1024.
__global__ __launch_bounds__(256)
void ln_k(const float* __restrict__ in, const float* __restrict__ in2,
          const float* __restrict__ w, const float* __restrict__ b,
          float* __restrict__ outf, u16* __restrict__ outb) {
  int row = blockIdx.x, t = threadIdx.x;
  const float4* ip = (const float4*)(in + (size_t)row * 1024);
  float4 x = ip[t];
  if (in2) {
    const float4* ip2 = (const float4*)(in2 + (size_t)row * 1024);
    float4 o = ip2[t];
    x.x += o.x; x.y += o.y; x.z += o.z; x.w += o.w;
  }
  float s = x.x + x.y + x.z + x.w;
  float q = x.x * x.x + x.y * x.y + x.z * x.z + x.w * x.w;
#pragma unroll
  for (int m = 32; m; m >>= 1) { s += __shfl_xor(s, m); q += __shfl_xor(q, m); }
  __shared__ float rs[4], rq[4];
  if ((t & 63) == 0) { rs[t >> 6] = s; rq[t >> 6] = q; }
  __syncthreads();
  s = rs[0] + rs[1] + rs[2] + rs[3];
  q = rq[0] + rq[1] + rq[2] + rq[3];
  float mean = s * (1.f / 1024.f);
  float var  = q * (1.f / 1024.f) - mean * mean;
  float rstd = rsqrtf(var + 1e-5f);
  float4 wv = ((const float4*)w)[t];
  float4 bv = ((const float4*)b)[t];
  float4 y;
  y.x = (x.x - mean) * rstd * wv.x + bv.x;
  y.y = (x.y - mean) * rstd * wv.y + bv.y;
  y.z = (x.z - mean) * rstd * wv.z + bv.z;
  y.w = (x.w - mean) * rstd * wv.w + bv.w;
  if (outf) ((float4*)(outf + (size_t)row * 1024))[t] = y;
  ushort4 ub;
  ub.x = f2b(y.x); ub.y = f2b(y.y); ub.z = f2b(y.z); ub.w = f2b(y.w);
  ((ushort4*)(outb + (size_t)row * 1024))[t] = ub;
}

// ---------------------------------------------------------------------------
// 128x128 tile bf16 GEMM body, BK=64, 256 threads (4 waves, 2x2 of 64x64).
// XOR chunk swizzle -> conflict-free ds_read_b128. blockIdx.z = split-K slice.
// 2-phase LDS dbuf: stage k+1 BEFORE compute k, ONE barrier per K-step so the
// vmcnt(0) drain lands after the MFMA cluster (latency hidden). [R8, verified]
#define EPI_QKV  0
#define EPI_RELU 1
#define EPI_RES  2

// 0.125 * log2(e): folds the 1/sqrt(64) score scale AND the exp->exp2
// conversion into the Q projection (attention uses exp2 directly).
#define QSCALE 0.18033688011112042f

template <int EPI>
__device__ __forceinline__
void gemm_body(const u16* __restrict__ A, const u16* __restrict__ Bt,
               int K, int lda, int ldbt,
               const float* __restrict__ bias0, const float* __restrict__ bias1,
               const float* __restrict__ bias2, const float* __restrict__ res,
               int ldout, u16* __restrict__ outb, float* __restrict__ outf,
               float* __restrict__ outp) {
  __shared__ __align__(16) u16 As[2][128 * 64];
  __shared__ __align__(16) u16 Bs[2][128 * 64];
  int t = threadIdx.x;
  int wave = t >> 6, lane = t & 63, quad = lane >> 4, l16 = lane & 15;
  int x7 = l16 & 7;
  int wm = (wave >> 1) * 64, wn = (wave & 1) * 64;
  int bm = blockIdx.x * 128, bn = blockIdx.y * 128;
  int zoff = blockIdx.z * K;

  const u16* Agl[4];
  const u16* Bgl[4];
#pragma unroll
  for (int i = 0; i < 4; i++) {
    int idx = i * 256 + t, r = idx >> 3, c = (idx & 7) ^ (r & 7);
    Agl[i] = A + (size_t)(bm + r) * lda + zoff + c * 8;
    Bgl[i] = Bt + (size_t)(bn + r) * ldbt + zoff + c * 8;
  }

  f32x4 acc[4][4] = {};

  // prologue: stage tile 0 into buffer 0
#pragma unroll
  for (int i = 0; i < 4; i++) {
    gload16(Agl[i], (u16*)As[0] + t * 8 + i * 2048);
    gload16(Bgl[i], (u16*)Bs[0] + t * 8 + i * 2048);
  }
  __syncthreads();

  int nk = K >> 6;
  for (int kt = 0; kt < nk; kt++) {
    const u16* Ac = As[kt & 1];
    const u16* Bc = Bs[kt & 1];
    if (kt + 1 < nk) {
      int k1 = (kt + 1) << 6;
      u16* An = (u16*)As[(kt + 1) & 1] + t * 8;
      u16* Bn = (u16*)Bs[(kt + 1) & 1] + t * 8;
#pragma unroll
      for (int i = 0; i < 4; i++) {
        gload16(Agl[i] + k1, An + i * 2048);
        gload16(Bgl[i] + k1, Bn + i * 2048);
      }
    }
#pragma unroll
    for (int kc = 0; kc < 2; kc++) {
      bf16x8 af[4], bfr[4];
#pragma unroll
      for (int i = 0; i < 4; i++) {
        int r = wm + i * 16 + l16;
        af[i] = *(const bf16x8*)(Ac + r * 64 + (((kc * 4 + quad) ^ x7) * 8));
      }
#pragma unroll
      for (int j = 0; j < 4; j++) {
        int r = wn + j * 16 + l16;
        bfr[j] = *(const bf16x8*)(Bc + r * 64 + (((kc * 4 + quad) ^ x7) * 8));
      }
#pragma unroll
      for (int i = 0; i < 4; i++)
#pragma unroll
        for (int j = 0; j < 4; j++)
          acc[i][j] = __builtin_amdgcn_mfma_f32_16x16x32_bf16(af[i], bfr[j],
                                                              acc[i][j], 0, 0, 0);
    }
    // one barrier per K-step: waits (a) all waves done reading cur buffer,
    // (b) vmcnt(0) drain of next-tile global_load_lds -- after the MFMAs.
    __syncthreads();
  }

#pragma unroll
  for (int i = 0; i < 4; i++) {
#pragma unroll
    for (int j = 0; j < 4; j++) {
      int c = bn + wn + j * 16 + l16;
#pragma unroll
      for (int rr = 0; rr < 4; rr++) {
        int r = bm + wm + i * 16 + quad * 4 + rr;
        float v = acc[i][j][rr];
        if (EPI == EPI_QKV) {
          int which = c >> 10, h = (c >> 6) & 15, d = c & 63;
          const float* bp = which == 0 ? bias0 : (which == 1 ? bias1 : bias2);
          v += bp[h * 64 + d];
          if (which == 0) v *= QSCALE;  // prescale Q for base-2 softmax
          int bb = r >> 11, ss = r & 2047;
          outb[((size_t)(which * 32 + bb * 16 + h) * 2048 + ss) * 64 + d] = f2b(v);
        } else if (EPI == EPI_RELU) {
          v += bias0[c];
          v = v > 0.f ? v : 0.f;
          outb[(size_t)r * ldout + c] = f2b(v);
        } else {
          if (blockIdx.z == 0) {
            v += bias0[c] + res[(size_t)r * ldout + c];
            outf[(size_t)r * ldout + c] = v;
          } else {
            outp[(size_t)r * ldout + c] = v;
          }
        }
      }
    }
  }
}

__global__ __launch_bounds__(256)
void qkv_gemm(const u16* A, const u16* Bt, int K, int lda, int ldbt,
              const float* b0, const float* b1, const float* b2,
              u16* outb) {
  gemm_body<EPI_QKV>(A, Bt, K, lda, ldbt, b0, b1, b2, nullptr, 0, outb, nullptr, nullptr);
}
__global__ __launch_bounds__(256)
void ffn1_gemm(const u16* A, const u16* Bt, int K, int lda, int ldbt,
               const float* b0, int ldout, u16* outb) {
  gemm_body<EPI_RELU>(A, Bt, K, lda, ldbt, b0, nullptr, nullptr, nullptr, ldout, outb, nullptr, nullptr);
}
__global__ __launch_bounds__(256)
void ffn2_gemm(const u16* A, const u16* Bt, int K, int lda, int ldbt,
               const float* b0, const float* res, int ldout,
               float* outf, float* outp) {
  gemm_body<EPI_RES>(A, Bt, K, lda, ldbt, b0, nullptr, nullptr, res, ldout, nullptr, outf, outp);
}

// out[i] += part[i]  (fp32, float4)
__global__ __launch_bounds__(256)
void reduce_k(float* __restrict__ out, const float* __restrict__ part) {
  int i = blockIdx.x * 256 + threadIdx.x;
  float4 a = ((const float4*)part)[i];
  float4 b = ((float4*)out)[i];
  b.x += a.x; b.y += a.y; b.z += a.z; b.w += a.w;
  ((float4*)out)[i] = b;
}

// ---------------------------------------------------------------------------
// Flash attention, causal. Grid (16, 32), 512 threads (8 waves).
// R14: + setprio(1) around QK^T/PV MFMA clusters (T5, m191) and defer-max
// with THR=8 in the base-2 domain (T13): when every row's new tile-max is
// within 8 of the running max, keep the old max -- P<=2^8, skip the O-rescale
// and the LDS-aux alpha roundtrip. Exact math (common reference max).
__global__ __launch_bounds__(512, 6)
void attn_k(const u16* __restrict__ qkv, const u16* __restrict__ vt,
            float* __restrict__ o) {
  int bh = blockIdx.y, b = bh >> 4, h = bh & 15;
  int Qt = b ? (15 - (int)blockIdx.x) : (int)blockIdx.x;  // causal balance
  int t = threadIdx.x;
  int wave = t >> 6, lane = t & 63, quad = lane >> 4, l16 = lane & 15;
  int x7 = l16 & 7;
  int q0 = Qt * 128 + wave * 16;

  const u16* qg = qkv + (size_t)bh * (2048 * 64);
  const u16* kg = qkv + (size_t)(32 + bh) * (2048 * 64);
  const u16* vg = vt + (size_t)bh * (64 * 2048);  // [dh][s]

  __shared__ __align__(16) u16 Ks[2][64 * 64];
  __shared__ __align__(16) u16 Vs[2][64 * 64];
  __shared__ __align__(16) u16 Ps[8][16 * 64 + 32];  // +64B aux per wave
  u16* Pw = Ps[wave];
  float* auxf = (float*)(Pw + 1024);

  int sr = t >> 3, sc_ = (t & 7) ^ (sr & 7);

  gload16(kg + (size_t)sr * 64 + sc_ * 8, Ks[0] + t * 8);
  gload16(vg + (size_t)sr * 2048 + sc_ * 8, Vs[0] + t * 8);

  bf16x8 qf0 = ld16(qg + (size_t)(q0 + l16) * 64 + quad * 8);
  bf16x8 qf1 = ld16(qg + (size_t)(q0 + l16) * 64 + 32 + quad * 8);

  f32x4 oacc[4] = {};
  float mo = NEG_INF, ll = 0.f;
  int kmax_w = q0 >> 6;
  int klast = 2 * Qt + 1;

  __syncthreads();

  for (int kt = 0; kt <= klast; kt++) {
    const u16* ks = Ks[kt & 1];
    const u16* vs = Vs[kt & 1];
    if (kt < klast) {
      gload16(kg + (size_t)((kt + 1) * 64 + sr) * 64 + sc_ * 8, Ks[(kt + 1) & 1] + t * 8);
      gload16(vg + (size_t)sr * 2048 + (kt + 1) * 64 + sc_ * 8, Vs[(kt + 1) & 1] + t * 8);
    }
    if (kt <= kmax_w) {
      // ---- S^T: A = K rows (m = kv), B = Q rows (n = q) ----
      f32x4 sc[4];
      __builtin_amdgcn_s_setprio(1);
#pragma unroll
      for (int g = 0; g < 4; g++) {
        const u16* kr = ks + (g * 16 + l16) * 64;
        bf16x8 kf0 = *(const bf16x8*)(kr + ((quad ^ x7) * 8));
        bf16x8 kf1 = *(const bf16x8*)(kr + (((4 + quad) ^ x7) * 8));
        f32x4 s = {};
        s = __builtin_amdgcn_mfma_f32_16x16x32_bf16(kf0, qf0, s, 0, 0, 0);
        s = __builtin_amdgcn_mfma_f32_16x16x32_bf16(kf1, qf1, s, 0, 0, 0);
        sc[g] = s;
      }
      __builtin_amdgcn_s_setprio(0);

      if (kt == kmax_w) {  // diagonal tile: mask kv > q
#pragma unroll
        for (int g = 0; g < 4; g++) {
          int kvb = kt * 64 + g * 16 + quad * 4;
#pragma unroll
          for (int rr = 0; rr < 4; rr++)
            if (kvb + rr > q0 + l16) sc[g][rr] = NEG_INF;
        }
      }

      // ---- online softmax, row = q = l16 ----
      float mx = sc[0][0];
#pragma unroll
      for (int g = 0; g < 4; g++)
#pragma unroll
        for (int rr = 0; rr < 4; rr++) mx = fmaxf(mx, sc[g][rr]);
      mx = fmaxf(mx, __shfl_xor(mx, 16));
      mx = fmaxf(mx, __shfl_xor(mx, 32));

      // T13 defer-max: if all rows' tile-max is within THR of the running
      // max, keep mo (P <= 2^8; exact -- common reference max). First tile:
      // mo = -inf -> mx - mo = +inf -> no skip.
      bool skip = __all(mx - mo <= 8.f);
      float mnew = skip ? mo : fmaxf(mo, mx);

      float sum = 0.f;
#pragma unroll
      for (int g = 0; g < 4; g++) {
        float p0 = EXP2F(sc[g][0] - mnew);
        float p1 = EXP2F(sc[g][1] - mnew);
        float p2 = EXP2F(sc[g][2] - mnew);
        float p3 = EXP2F(sc[g][3] - mnew);
        sum += (p0 + p1) + (p2 + p3);
        u32 lo = pack_bf16_trunc(p0, p1);
        u32 hi = pack_bf16_trunc(p2, p3);
        int slot = (2 * g + (quad >> 1)) ^ x7;
        *(uint2*)(Pw + l16 * 64 + slot * 8 + (quad & 1) * 4) = make_uint2(lo, hi);
      }
      sum += __shfl_xor(sum, 16);
      sum += __shfl_xor(sum, 32);

      if (!skip) {
        float al = EXP2F(mo - mnew);
        mo = mnew;
        ll = ll * al + sum;
        // rescale O: alpha indexed by q=l16 -> broadcast via per-wave LDS aux
        if (lane < 16) auxf[lane] = al;
        f32x4 av = *(const f32x4*)(auxf + quad * 4);
#pragma unroll
        for (int g = 0; g < 4; g++)
#pragma unroll
          for (int rr = 0; rr < 4; rr++) oacc[g][rr] *= av[rr];
      } else {
        ll += sum;
      }

      // ---- O += P(A) x V^T(B) ----
      bf16x8 pf0 = *(const bf16x8*)(Pw + l16 * 64 + ((quad ^ x7) * 8));
      bf16x8 pf1 = *(const bf16x8*)(Pw + l16 * 64 + (((4 + quad) ^ x7) * 8));
      __builtin_amdgcn_s_setprio(1);
#pragma unroll
      for (int g = 0; g < 4; g++) {
        const u16* vr = vs + (g * 16 + l16) * 64;
        bf16x8 vf0 = *(const bf16x8*)(vr + ((quad ^ x7) * 8));
        bf16x8 vf1 = *(const bf16x8*)(vr + (((4 + quad) ^ x7) * 8));
        oacc[g] = __builtin_amdgcn_mfma_f32_16x16x32_bf16(pf0, vf0, oacc[g], 0, 0, 0);
        oacc[g] = __builtin_amdgcn_mfma_f32_16x16x32_bf16(pf1, vf1, oacc[g], 0, 0, 0);
      }
      __builtin_amdgcn_s_setprio(0);
    }
    __syncthreads();
  }

  // epilogue: O row = m = quad*4+rr, col = dh = g*16+l16; l indexed by l16
  if (lane < 16) auxf[lane] = ll;
  f32x4 lv = *(const f32x4*)(auxf + quad * 4);
  float rinv[4];
#pragma unroll
  for (int rr = 0; rr < 4; rr++) rinv[rr] = 1.f / lv[rr];
  float* op = o + ((size_t)b * 2048 + q0) * 1024 + h * 64;
#pragma unroll
  for (int g = 0; g < 4; g++)
#pragma unroll
    for (int rr = 0; rr < 4; rr++)
      op[(size_t)(quad * 4 + rr) * 1024 + g * 16 + l16] = oacc[g][rr] * rinv[rr];
}

// ---------------------------------------------------------------------------
extern "C" void kernel_launch(void* const* d_in, const int* in_sizes, int n_in,
                              void* d_out, int out_size, void* d_ws, size_t ws_size,
                              hipStream_t stream) {
  const float* emb  = (const float*)d_in[0];
  const float* Wq   = (const float*)d_in[1];
  const float* bq   = (const float*)d_in[2];
  const float* Wk   = (const float*)d_in[3];
  const float* bk   = (const float*)d_in[4];
  const float* Wv   = (const float*)d_in[5];
  const float* bv   = (const float*)d_in[6];
  const float* ln1w = (const float*)d_in[7];
  const float* ln1b = (const float*)d_in[8];
  const float* ln2w = (const float*)d_in[9];
  const float* ln2b = (const float*)d_in[10];
  const float* W1   = (const float*)d_in[11];
  const float* b1   = (const float*)d_in[12];
  const float* W2   = (const float*)d_in[13];
  const float* b2   = (const float*)d_in[14];
  float* out = (float*)d_out;

  char* p = (char*)d_ws;
  u16*   Wqkv_t = (u16*)p;   p += (size_t)3072 * 1024 * 2;
  u16*   W1t    = (u16*)p;   p += (size_t)4096 * 1024 * 2;
  u16*   W2t    = (u16*)p;   p += (size_t)1024 * 4096 * 2;
  float* x      = (float*)p; p += (size_t)4096 * 1024 * 4;
  u16*   xb     = (u16*)p;   p += (size_t)4096 * 1024 * 2;
  u16*   qkvb   = (u16*)p;   p += (size_t)3 * 32 * 2048 * 64 * 2;  // 25.2 MB
  float* ob     = (float*)p; p += (size_t)4096 * 1024 * 4;         // 16.8 MB
  float* y      = (float*)p; p += (size_t)4096 * 1024 * 4;
  u16*   yb     = (u16*)p;   p += (size_t)4096 * 1024 * 2;
  u16*   hb     = (u16*)qkvb; // alias: qkvb+ob (42 MB) dead before FFN1 writes hb (33.6 MB)
  u16*   vT     = (u16*)y;    // alias: vT (8.4 MB) dead before ln2 writes y
  float* part   = x;          // alias: x (16.8 MB fp32) dead before FFN2 z=1 partial
  if (ws_size < (size_t)(p - (char*)d_ws)) return;

  // all weight transposes in one launch: 1024 (W1) + 1024 (W2) + 768 (QKV)
  transpose_all_k<<<dim3(2816), 256, 0, stream>>>(
      W1, W2, Wq, Wk, Wv, W1t, W2t, Wqkv_t);

  ln_k<<<dim3(4096), 256, 0, stream>>>(emb, nullptr, ln1w, ln1b, x, xb);

  qkv_gemm<<<dim3(32, 24, 1), 256, 0, stream>>>(
      xb, Wqkv_t, 1024, 1024, 1024, bq, bk, bv, qkvb);

  vtrans_k<<<dim3(32, 32), 256, 0, stream>>>(qkvb + (size_t)64 * 2048 * 64, vT);

  attn_k<<<dim3(16, 32), 512, 0, stream>>>(qkvb, vT, ob);

  ln_k<<<dim3(4096), 256, 0, stream>>>(x, ob, ln2w, ln2b, y, yb);

  ffn1_gemm<<<dim3(32, 32, 1), 256, 0, stream>>>(
      yb, W1t, 1024, 1024, 1024, b1, 4096, hb);

  // FFN2 split-K=2: z=0 -> out (+b2+y), z=1 -> raw partial into `part`
  ffn2_gemm<<<dim3(32, 8, 2), 256, 0, stream>>>(
      hb, W2t, 2048, 4096, 4096, b2, y, 1024, out, part);

  reduce_k<<<dim3(4096), 256, 0, stream>>>(out, part);
}

// Round 9
// 329.792 us; speedup vs baseline: 1.0125x; 1.0013x over previous
//
#include <hip/hip_runtime.h>

// TransformerLayer on MI355X (gfx950), bf16 MFMA pipeline, fp32 LN/softmax/accum.
// R15 == R12 exact (session best, 326.7us verified). Final state.
// - GEMMs: 128x128/BK=64 2-phase LDS dbuf (stage-next -> MFMA -> one barrier),
//   2 blocks/CU; ffn2 split-K=2 + fp32 partial + reduce. Structure ceiling
//   ~625 TF; escape routes all tested & closed (R7 splitK4, R9-R11 8-phase x3,
//   R13 256-tile@2ph).
// - attn: R5-lineage flash attention (S^T orientation, LDS K/V dbuf, in-reg
//   softmax, v_perm P-pack). R14's setprio/defer-max were net-negative here
//   (lockstep 8-wave blocks = m190 regime) -- excluded.
// - transposes fused into one launch; ln/vtrans/reduce at BW.

typedef unsigned short u16;
typedef unsigned int   u32;
typedef __bf16 bf16x8 __attribute__((ext_vector_type(8)));
typedef float  f32x4  __attribute__((ext_vector_type(4)));

#define NEG_INF (-__builtin_inff())

#if __has_builtin(__builtin_amdgcn_exp2f)
#define EXP2F(x) __builtin_amdgcn_exp2f(x)
#else
#define EXP2F(x) exp2f(x)
#endif

// pack: result = lo16:=a.hi16, hi16:=b.hi16 (trunc bf16 pair)
__device__ __forceinline__ u32 pack_bf16_trunc(float a, float b) {
#if __has_builtin(__builtin_amdgcn_perm)
  return __builtin_amdgcn_perm(__float_as_uint(b), __float_as_uint(a), 0x07060302u);
#else
  return (__float_as_uint(a) >> 16) | (__float_as_uint(b) & 0xFFFF0000u);
#endif
}

// fp32 -> bf16 RNE (finite inputs only)
__device__ __forceinline__ u16 f2b(float f) {
  u32 u = __float_as_uint(f);
  u = (u + 0x7fffu + ((u >> 16) & 1u)) >> 16;
  return (u16)u;
}

// async global->LDS, 16B per lane. LDS dest must be wave-uniform base + lane*16.
__device__ __forceinline__ void gload16(const void* g, void* l) {
  __builtin_amdgcn_global_load_lds(
      (const __attribute__((address_space(1))) u32*)g,
      (__attribute__((address_space(3))) u32*)l, 16, 0, 0);
}

__device__ __forceinline__ bf16x8 ld16(const u16* p) { return *(const bf16x8*)p; }

// ---------------------------------------------------------------------------
// ALL weight transposes (fp32 -> bf16, [R][C] -> [C][R]) in ONE flat launch.
// id <  1024: W1 (1024x4096) -> W1t [4096][1024]
// id <  2048: W2 (4096x1024) -> W2t [1024][4096]
// id >= 2048: Wq/Wk/Wv head-matrices ([1024][64] each, 48 total) ->
//             Wqkv_t: which*1M + (sub*64 + c)*1024 + r   (= [64][1024]/head)
__global__ __launch_bounds__(256)
void transpose_all_k(const float* __restrict__ W1, const float* __restrict__ W2,
                     const float* __restrict__ Wq, const float* __restrict__ Wk,
                     const float* __restrict__ Wv,
                     u16* __restrict__ W1t, u16* __restrict__ W2t,
                     u16* __restrict__ Wqkv_t) {
  __shared__ float tile[64][65];
  int id = blockIdx.x;
  const float* in; u16* out; int R, C, r0, c0;
  if (id < 1024) {
    in = W1; out = W1t; R = 1024; C = 4096;
    r0 = (id & 15) * 64; c0 = (id >> 4) * 64;
  } else if (id < 2048) {
    id -= 1024;
    in = W2; out = W2t; R = 4096; C = 1024;
    r0 = (id >> 4) * 64; c0 = (id & 15) * 64;
  } else {
    id -= 2048;                       // 0..767: 48 head-matrices x 16 row-chunks
    int z = id >> 4, which = z >> 4, sub = z & 15;
    const float* base = which == 0 ? Wq : (which == 1 ? Wk : Wv);
    in = base + (size_t)sub * 1024 * 64;
    out = Wqkv_t + (size_t)which * 1024 * 1024 + (size_t)sub * 64 * 1024;
    R = 1024; C = 64;
    r0 = (id & 15) * 64; c0 = 0;
  }
  int tr = threadIdx.x >> 6, tc = threadIdx.x & 63;
#pragma unroll
  for (int i = 0; i < 16; i++) {
    int r = i * 4 + tr;
    tile[r][tc] = in[(size_t)(r0 + r) * C + c0 + tc];
  }
  __syncthreads();
#pragma unroll
  for (int i = 0; i < 16; i++) {
    int c = i * 4 + tr;
    out[(size_t)(c0 + c) * R + r0 + tc] = f2b(tile[tc][c]);
  }
}

// ---------------------------------------------------------------------------
// bf16 transpose for V: vin [bh][2048][64] -> vt [bh][64][2048]
__global__ __launch_bounds__(256)
void vtrans_k(const u16* __restrict__ vin, u16* __restrict__ vt) {
  __shared__ __align__(16) u16 tile[64][72];
  int s0 = blockIdx.x * 64, bh = blockIdx.y;
  const u16* ip = vin + (size_t)bh * 2048 * 64;
  u16* op = vt + (size_t)bh * 64 * 2048;
  int t = threadIdx.x;
#pragma unroll
  for (int i = 0; i < 2; i++) {
    int idx = i * 256 + t, r = idx >> 3, c = idx & 7;
    *(uint4*)&tile[r][c * 8] = *(const uint4*)(ip + (size_t)(s0 + r) * 64 + c * 8);
  }
  __syncthreads();
#pragma unroll
  for (int i = 0; i < 16; i++) {
    int d = i * 4 + (t >> 6), s = t & 63;
    op[(size_t)d * 2048 + s0 + s] = tile[s][d];
  }
}

// ---------------------------------------------------------------------------
// LayerNorm over rows of 1024.
__global__ __launch_bounds__(256)
void ln_k(const float* __restrict__ in, const float* __restrict__ in2,
          const float* __restrict__ w, const float* __restrict__ b,
          float* __restrict__ outf, u16* __restrict__ outb) {
  int row = blockIdx.x, t = threadIdx.x;
  const float4* ip = (const float4*)(in + (size_t)row * 1024);
  float4 x = ip[t];
  if (in2) {
    const float4* ip2 = (const float4*)(in2 + (size_t)row * 1024);
    float4 o = ip2[t];
    x.x += o.x; x.y += o.y; x.z += o.z; x.w += o.w;
  }
  float s = x.x + x.y + x.z + x.w;
  float q = x.x * x.x + x.y * x.y + x.z * x.z + x.w * x.w;
#pragma unroll
  for (int m = 32; m; m >>= 1) { s += __shfl_xor(s, m); q += __shfl_xor(q, m); }
  __shared__ float rs[4], rq[4];
  if ((t & 63) == 0) { rs[t >> 6] = s; rq[t >> 6] = q; }
  __syncthreads();
  s = rs[0] + rs[1] + rs[2] + rs[3];
  q = rq[0] + rq[1] + rq[2] + rq[3];
  float mean = s * (1.f / 1024.f);
  float var  = q * (1.f / 1024.f) - mean * mean;
  float rstd = rsqrtf(var + 1e-5f);
  float4 wv = ((const float4*)w)[t];
  float4 bv = ((const float4*)b)[t];
  float4 y;
  y.x = (x.x - mean) * rstd * wv.x + bv.x;
  y.y = (x.y - mean) * rstd * wv.y + bv.y;
  y.z = (x.z - mean) * rstd * wv.z + bv.z;
  y.w = (x.w - mean) * rstd * wv.w + bv.w;
  if (outf) ((float4*)(outf + (size_t)row * 1024))[t] = y;
  ushort4 ub;
  ub.x = f2b(y.x); ub.y = f2b(y.y); ub.z = f2b(y.z); ub.w = f2b(y.w);
  ((ushort4*)(outb + (size_t)row * 1024))[t] = ub;
}

// ---------------------------------------------------------------------------
// 128x128 tile bf16 GEMM body, BK=64, 256 threads (4 waves, 2x2 of 64x64).
// XOR chunk swizzle -> conflict-free ds_read_b128. blockIdx.z = split-K slice.
// 2-phase LDS dbuf: stage k+1 BEFORE compute k, ONE barrier per K-step so the
// vmcnt(0) drain lands after the MFMA cluster (latency hidden). [R8, verified]
#define EPI_QKV  0
#define EPI_RELU 1
#define EPI_RES  2

// 0.125 * log2(e): folds the 1/sqrt(64) score scale AND the exp->exp2
// conversion into the Q projection (attention uses exp2 directly).
#define QSCALE 0.18033688011112042f

template <int EPI>
__device__ __forceinline__
void gemm_body(const u16* __restrict__ A, const u16* __restrict__ Bt,
               int K, int lda, int ldbt,
               const float* __restrict__ bias0, const float* __restrict__ bias1,
               const float* __restrict__ bias2, const float* __restrict__ res,
               int ldout, u16* __restrict__ outb, float* __restrict__ outf,
               float* __restrict__ outp) {
  __shared__ __align__(16) u16 As[2][128 * 64];
  __shared__ __align__(16) u16 Bs[2][128 * 64];
  int t = threadIdx.x;
  int wave = t >> 6, lane = t & 63, quad = lane >> 4, l16 = lane & 15;
  int x7 = l16 & 7;
  int wm = (wave >> 1) * 64, wn = (wave & 1) * 64;
  int bm = blockIdx.x * 128, bn = blockIdx.y * 128;
  int zoff = blockIdx.z * K;

  const u16* Agl[4];
  const u16* Bgl[4];
#pragma unroll
  for (int i = 0; i < 4; i++) {
    int idx = i * 256 + t, r = idx >> 3, c = (idx & 7) ^ (r & 7);
    Agl[i] = A + (size_t)(bm + r) * lda + zoff + c * 8;
    Bgl[i] = Bt + (size_t)(bn + r) * ldbt + zoff + c * 8;
  }

  f32x4 acc[4][4] = {};

  // prologue: stage tile 0 into buffer 0
#pragma unroll
  for (int i = 0; i < 4; i++) {
    gload16(Agl[i], (u16*)As[0] + t * 8 + i * 2048);
    gload16(Bgl[i], (u16*)Bs[0] + t * 8 + i * 2048);
  }
  __syncthreads();

  int nk = K >> 6;
  for (int kt = 0; kt < nk; kt++) {
    const u16* Ac = As[kt & 1];
    const u16* Bc = Bs[kt & 1];
    if (kt + 1 < nk) {
      int k1 = (kt + 1) << 6;
      u16* An = (u16*)As[(kt + 1) & 1] + t * 8;
      u16* Bn = (u16*)Bs[(kt + 1) & 1] + t * 8;
#pragma unroll
      for (int i = 0; i < 4; i++) {
        gload16(Agl[i] + k1, An + i * 2048);
        gload16(Bgl[i] + k1, Bn + i * 2048);
      }
    }
#pragma unroll
    for (int kc = 0; kc < 2; kc++) {
      bf16x8 af[4], bfr[4];
#pragma unroll
      for (int i = 0; i < 4; i++) {
        int r = wm + i * 16 + l16;
        af[i] = *(const bf16x8*)(Ac + r * 64 + (((kc * 4 + quad) ^ x7) * 8));
      }
#pragma unroll
      for (int j = 0; j < 4; j++) {
        int r = wn + j * 16 + l16;
        bfr[j] = *(const bf16x8*)(Bc + r * 64 + (((kc * 4 + quad) ^ x7) * 8));
      }
#pragma unroll
      for (int i = 0; i < 4; i++)
#pragma unroll
        for (int j = 0; j < 4; j++)
          acc[i][j] = __builtin_amdgcn_mfma_f32_16x16x32_bf16(af[i], bfr[j],
                                                              acc[i][j], 0, 0, 0);
    }
    // one barrier per K-step: waits (a) all waves done reading cur buffer,
    // (b) vmcnt(0) drain of next-tile global_load_lds -- after the MFMAs.
    __syncthreads();
  }

#pragma unroll
  for (int i = 0; i < 4; i++) {
#pragma unroll
    for (int j = 0; j < 4; j++) {
      int c = bn + wn + j * 16 + l16;
#pragma unroll
      for (int rr = 0; rr < 4; rr++) {
        int r = bm + wm + i * 16 + quad * 4 + rr;
        float v = acc[i][j][rr];
        if (EPI == EPI_QKV) {
          int which = c >> 10, h = (c >> 6) & 15, d = c & 63;
          const float* bp = which == 0 ? bias0 : (which == 1 ? bias1 : bias2);
          v += bp[h * 64 + d];
          if (which == 0) v *= QSCALE;  // prescale Q for base-2 softmax
          int bb = r >> 11, ss = r & 2047;
          outb[((size_t)(which * 32 + bb * 16 + h) * 2048 + ss) * 64 + d] = f2b(v);
        } else if (EPI == EPI_RELU) {
          v += bias0[c];
          v = v > 0.f ? v : 0.f;
          outb[(size_t)r * ldout + c] = f2b(v);
        } else {
          if (blockIdx.z == 0) {
            v += bias0[c] + res[(size_t)r * ldout + c];
            outf[(size_t)r * ldout + c] = v;
          } else {
            outp[(size_t)r * ldout + c] = v;
          }
        }
      }
    }
  }
}

__global__ __launch_bounds__(256)
void qkv_gemm(const u16* A, const u16* Bt, int K, int lda, int ldbt,
              const float* b0, const float* b1, const float* b2,
              u16* outb) {
  gemm_body<EPI_QKV>(A, Bt, K, lda, ldbt, b0, b1, b2, nullptr, 0, outb, nullptr, nullptr);
}
__global__ __launch_bounds__(256)
void ffn1_gemm(const u16* A, const u16* Bt, int K, int lda, int ldbt,
               const float* b0, int ldout, u16* outb) {
  gemm_body<EPI_RELU>(A, Bt, K, lda, ldbt, b0, nullptr, nullptr, nullptr, ldout, outb, nullptr, nullptr);
}
__global__ __launch_bounds__(256)
void ffn2_gemm(const u16* A, const u16* Bt, int K, int lda, int ldbt,
               const float* b0, const float* res, int ldout,
               float* outf, float* outp) {
  gemm_body<EPI_RES>(A, Bt, K, lda, ldbt, b0, nullptr, nullptr, res, ldout, nullptr, outf, outp);
}

// out[i] += part[i]  (fp32, float4)
__global__ __launch_bounds__(256)
void reduce_k(float* __restrict__ out, const float* __restrict__ part) {
  int i = blockIdx.x * 256 + threadIdx.x;
  float4 a = ((const float4*)part)[i];
  float4 b = ((float4*)out)[i];
  b.x += a.x; b.y += a.y; b.z += a.z; b.w += a.w;
  ((float4*)out)[i] = b;
}

// ---------------------------------------------------------------------------
// Flash attention v5, causal. Grid (16, 32), 512 threads (8 waves).
// LDS-staged K/V dbuf, 1 barrier/iter, S^T orientation, 2-shuffle softmax rows,
// raw v_exp_f32, v_perm P-pack, alpha broadcast via per-wave LDS aux. [verified]
__global__ __launch_bounds__(512, 6)
void attn_k(const u16* __restrict__ qkv, const u16* __restrict__ vt,
            float* __restrict__ o) {
  int bh = blockIdx.y, b = bh >> 4, h = bh & 15;
  int Qt = b ? (15 - (int)blockIdx.x) : (int)blockIdx.x;  // causal balance
  int t = threadIdx.x;
  int wave = t >> 6, lane = t & 63, quad = lane >> 4, l16 = lane & 15;
  int x7 = l16 & 7;
  int q0 = Qt * 128 + wave * 16;

  const u16* qg = qkv + (size_t)bh * (2048 * 64);
  const u16* kg = qkv + (size_t)(32 + bh) * (2048 * 64);
  const u16* vg = vt + (size_t)bh * (64 * 2048);  // [dh][s]

  __shared__ __align__(16) u16 Ks[2][64 * 64];
  __shared__ __align__(16) u16 Vs[2][64 * 64];
  __shared__ __align__(16) u16 Ps[8][16 * 64 + 32];  // +64B aux per wave
  u16* Pw = Ps[wave];
  float* auxf = (float*)(Pw + 1024);

  int sr = t >> 3, sc_ = (t & 7) ^ (sr & 7);

  gload16(kg + (size_t)sr * 64 + sc_ * 8, Ks[0] + t * 8);
  gload16(vg + (size_t)sr * 2048 + sc_ * 8, Vs[0] + t * 8);

  bf16x8 qf0 = ld16(qg + (size_t)(q0 + l16) * 64 + quad * 8);
  bf16x8 qf1 = ld16(qg + (size_t)(q0 + l16) * 64 + 32 + quad * 8);

  f32x4 oacc[4] = {};
  float mo = NEG_INF, ll = 0.f;
  int kmax_w = q0 >> 6;
  int klast = 2 * Qt + 1;

  __syncthreads();

  for (int kt = 0; kt <= klast; kt++) {
    const u16* ks = Ks[kt & 1];
    const u16* vs = Vs[kt & 1];
    if (kt < klast) {
      gload16(kg + (size_t)((kt + 1) * 64 + sr) * 64 + sc_ * 8, Ks[(kt + 1) & 1] + t * 8);
      gload16(vg + (size_t)sr * 2048 + (kt + 1) * 64 + sc_ * 8, Vs[(kt + 1) & 1] + t * 8);
    }
    if (kt <= kmax_w) {
      // ---- S^T: A = K rows (m = kv), B = Q rows (n = q) ----
      f32x4 sc[4];
#pragma unroll
      for (int g = 0; g < 4; g++) {
        const u16* kr = ks + (g * 16 + l16) * 64;
        bf16x8 kf0 = *(const bf16x8*)(kr + ((quad ^ x7) * 8));
        bf16x8 kf1 = *(const bf16x8*)(kr + (((4 + quad) ^ x7) * 8));
        f32x4 s = {};
        s = __builtin_amdgcn_mfma_f32_16x16x32_bf16(kf0, qf0, s, 0, 0, 0);
        s = __builtin_amdgcn_mfma_f32_16x16x32_bf16(kf1, qf1, s, 0, 0, 0);
        sc[g] = s;
      }

      if (kt == kmax_w) {  // diagonal tile: mask kv > q
#pragma unroll
        for (int g = 0; g < 4; g++) {
          int kvb = kt * 64 + g * 16 + quad * 4;
#pragma unroll
          for (int rr = 0; rr < 4; rr++)
            if (kvb + rr > q0 + l16) sc[g][rr] = NEG_INF;
        }
      }

      // ---- online softmax, row = q = l16 ----
      float mx = sc[0][0];
#pragma unroll
      for (int g = 0; g < 4; g++)
#pragma unroll
        for (int rr = 0; rr < 4; rr++) mx = fmaxf(mx, sc[g][rr]);
      mx = fmaxf(mx, __shfl_xor(mx, 16));
      mx = fmaxf(mx, __shfl_xor(mx, 32));
      float mnew = fmaxf(mo, mx);
      float al = EXP2F(mo - mnew);
      mo = mnew;

      float sum = 0.f;
#pragma unroll
      for (int g = 0; g < 4; g++) {
        float p0 = EXP2F(sc[g][0] - mnew);
        float p1 = EXP2F(sc[g][1] - mnew);
        float p2 = EXP2F(sc[g][2] - mnew);
        float p3 = EXP2F(sc[g][3] - mnew);
        sum += (p0 + p1) + (p2 + p3);
        u32 lo = pack_bf16_trunc(p0, p1);
        u32 hi = pack_bf16_trunc(p2, p3);
        int slot = (2 * g + (quad >> 1)) ^ x7;
        *(uint2*)(Pw + l16 * 64 + slot * 8 + (quad & 1) * 4) = make_uint2(lo, hi);
      }
      sum += __shfl_xor(sum, 16);
      sum += __shfl_xor(sum, 32);
      ll = ll * al + sum;

      // rescale O: alpha indexed by q=l16 -> broadcast via per-wave LDS aux
      if (lane < 16) auxf[lane] = al;
      f32x4 av = *(const f32x4*)(auxf + quad * 4);
#pragma unroll
      for (int g = 0; g < 4; g++)
#pragma unroll
        for (int rr = 0; rr < 4; rr++) oacc[g][rr] *= av[rr];

      // ---- O += P(A) x V^T(B) ----
      bf16x8 pf0 = *(const bf16x8*)(Pw + l16 * 64 + ((quad ^ x7) * 8));
      bf16x8 pf1 = *(const bf16x8*)(Pw + l16 * 64 + (((4 + quad) ^ x7) * 8));
#pragma unroll
      for (int g = 0; g < 4; g++) {
        const u16* vr = vs + (g * 16 + l16) * 64;
        bf16x8 vf0 = *(const bf16x8*)(vr + ((quad ^ x7) * 8));
        bf16x8 vf1 = *(const bf16x8*)(vr + (((4 + quad) ^ x7) * 8));
        oacc[g] = __builtin_amdgcn_mfma_f32_16x16x32_bf16(pf0, vf0, oacc[g], 0, 0, 0);
        oacc[g] = __builtin_amdgcn_mfma_f32_16x16x32_bf16(pf1, vf1, oacc[g], 0, 0, 0);
      }
    }
    __syncthreads();
  }

  // epilogue: O row = m = quad*4+rr, col = dh = g*16+l16; l indexed by l16
  if (lane < 16) auxf[lane] = ll;
  f32x4 lv = *(const f32x4*)(auxf + quad * 4);
  float rinv[4];
#pragma unroll
  for (int rr = 0; rr < 4; rr++) rinv[rr] = 1.f / lv[rr];
  float* op = o + ((size_t)b * 2048 + q0) * 1024 + h * 64;
#pragma unroll
  for (int g = 0; g < 4; g++)
#pragma unroll
    for (int rr = 0; rr < 4; rr++)
      op[(size_t)(quad * 4 + rr) * 1024 + g * 16 + l16] = oacc[g][rr] * rinv[rr];
}

// ---------------------------------------------------------------------------
extern "C" void kernel_launch(void* const* d_in, const int* in_sizes, int n_in,
                              void* d_out, int out_size, void* d_ws, size_t ws_size,
                              hipStream_t stream) {
  const float* emb  = (const float*)d_in[0];
  const float* Wq   = (const float*)d_in[1];
  const float* bq   = (const float*)d_in[2];
  const float* Wk   = (const float*)d_in[3];
  const float* bk   = (const float*)d_in[4];
  const float* Wv   = (const float*)d_in[5];
  const float* bv   = (const float*)d_in[6];
  const float* ln1w = (const float*)d_in[7];
  const float* ln1b = (const float*)d_in[8];
  const float* ln2w = (const float*)d_in[9];
  const float* ln2b = (const float*)d_in[10];
  const float* W1   = (const float*)d_in[11];
  const float* b1   = (const float*)d_in[12];
  const float* W2   = (const float*)d_in[13];
  const float* b2   = (const float*)d_in[14];
  float* out = (float*)d_out;

  char* p = (char*)d_ws;
  u16*   Wqkv_t = (u16*)p;   p += (size_t)3072 * 1024 * 2;
  u16*   W1t    = (u16*)p;   p += (size_t)4096 * 1024 * 2;
  u16*   W2t    = (u16*)p;   p += (size_t)1024 * 4096 * 2;
  float* x      = (float*)p; p += (size_t)4096 * 1024 * 4;
  u16*   xb     = (u16*)p;   p += (size_t)4096 * 1024 * 2;
  u16*   qkvb   = (u16*)p;   p += (size_t)3 * 32 * 2048 * 64 * 2;  // 25.2 MB
  float* ob     = (float*)p; p += (size_t)4096 * 1024 * 4;         // 16.8 MB
  float* y      = (float*)p; p += (size_t)4096 * 1024 * 4;
  u16*   yb     = (u16*)p;   p += (size_t)4096 * 1024 * 2;
  u16*   hb     = (u16*)qkvb; // alias: qkvb+ob (42 MB) dead before FFN1 writes hb (33.6 MB)
  u16*   vT     = (u16*)y;    // alias: vT (8.4 MB) dead before ln2 writes y
  float* part   = x;          // alias: x (16.8 MB fp32) dead before FFN2 z=1 partial
  if (ws_size < (size_t)(p - (char*)d_ws)) return;

  // all weight transposes in one launch: 1024 (W1) + 1024 (W2) + 768 (QKV)
  transpose_all_k<<<dim3(2816), 256, 0, stream>>>(
      W1, W2, Wq, Wk, Wv, W1t, W2t, Wqkv_t);

  ln_k<<<dim3(4096), 256, 0, stream>>>(emb, nullptr, ln1w, ln1b, x, xb);

  qkv_gemm<<<dim3(32, 24, 1), 256, 0, stream>>>(
      xb, Wqkv_t, 1024, 1024, 1024, bq, bk, bv, qkvb);

  vtrans_k<<<dim3(32, 32), 256, 0, stream>>>(qkvb + (size_t)64 * 2048 * 64, vT);

  attn_k<<<dim3(16, 32), 512, 0, stream>>>(qkvb, vT, ob);

  ln_k<<<dim3(4096), 256, 0, stream>>>(x, ob, ln2w, ln2b, y, yb);

  ffn1_gemm<<<dim3(32, 32, 1), 256, 0, stream>>>(
      yb, W1t, 1024, 1024, 1024, b1, 4096, hb);

  // FFN2 split-K=2: z=0 -> out (+b2+y), z=1 -> raw partial into `part`
  ffn2_gemm<<<dim3(32, 8, 2), 256, 0, stream>>>(
      hb, W2t, 2048, 4096, 4096, b2, y, 1024, out, part);

  reduce_k<<<dim3(4096), 256, 0, stream>>>(out, part);
}

// Round 10
// 324.862 us; speedup vs baseline: 1.0278x; 1.0152x over previous
//
#include <hip/hip_runtime.h>

// TransformerLayer on MI355X (gfx950), bf16 MFMA pipeline, fp32 LN/softmax/accum.
// R16 = R15/R12 (session best, 326.7-329.8us verified) + launch fusion:
// transpose_all + ln1 are data-independent -> merged into one prep_k launch
// (blockIdx-partitioned; both bodies byte-identical to their verified forms).
// All hot kernels at their verified structure ceilings:
// - GEMMs: 128x128/BK=64 2-phase LDS dbuf, 2 blocks/CU (~625 TF). Escapes all
//   tested & closed: R7 splitK4, R9-R11 8-phase x3, R13 256-tile@2ph.
// - attn: R5-lineage flash attn; R14 setprio/defer-max net-negative (lockstep
//   8-wave blocks = m190 regime) -- excluded.

typedef unsigned short u16;
typedef unsigned int   u32;
typedef __bf16 bf16x8 __attribute__((ext_vector_type(8)));
typedef float  f32x4  __attribute__((ext_vector_type(4)));

#define NEG_INF (-__builtin_inff())

#if __has_builtin(__builtin_amdgcn_exp2f)
#define EXP2F(x) __builtin_amdgcn_exp2f(x)
#else
#define EXP2F(x) exp2f(x)
#endif

// pack: result = lo16:=a.hi16, hi16:=b.hi16 (trunc bf16 pair)
__device__ __forceinline__ u32 pack_bf16_trunc(float a, float b) {
#if __has_builtin(__builtin_amdgcn_perm)
  return __builtin_amdgcn_perm(__float_as_uint(b), __float_as_uint(a), 0x07060302u);
#else
  return (__float_as_uint(a) >> 16) | (__float_as_uint(b) & 0xFFFF0000u);
#endif
}

// fp32 -> bf16 RNE (finite inputs only)
__device__ __forceinline__ u16 f2b(float f) {
  u32 u = __float_as_uint(f);
  u = (u + 0x7fffu + ((u >> 16) & 1u)) >> 16;
  return (u16)u;
}

// async global->LDS, 16B per lane. LDS dest must be wave-uniform base + lane*16.
__device__ __forceinline__ void gload16(const void* g, void* l) {
  __builtin_amdgcn_global_load_lds(
      (const __attribute__((address_space(1))) u32*)g,
      (__attribute__((address_space(3))) u32*)l, 16, 0, 0);
}

__device__ __forceinline__ bf16x8 ld16(const u16* p) { return *(const bf16x8*)p; }

// ---------------------------------------------------------------------------
// LN body (verified ln_k), shared by prep_k (ln1) and ln_k (ln2).
__device__ __forceinline__
void ln_body(int row, const float* __restrict__ in, const float* __restrict__ in2,
             const float* __restrict__ w, const float* __restrict__ b,
             float* __restrict__ outf, u16* __restrict__ outb,
             float* rs, float* rq) {
  int t = threadIdx.x;
  const float4* ip = (const float4*)(in + (size_t)row * 1024);
  float4 x = ip[t];
  if (in2) {
    const float4* ip2 = (const float4*)(in2 + (size_t)row * 1024);
    float4 o = ip2[t];
    x.x += o.x; x.y += o.y; x.z += o.z; x.w += o.w;
  }
  float s = x.x + x.y + x.z + x.w;
  float q = x.x * x.x + x.y * x.y + x.z * x.z + x.w * x.w;
#pragma unroll
  for (int m = 32; m; m >>= 1) { s += __shfl_xor(s, m); q += __shfl_xor(q, m); }
  if ((t & 63) == 0) { rs[t >> 6] = s; rq[t >> 6] = q; }
  __syncthreads();
  s = rs[0] + rs[1] + rs[2] + rs[3];
  q = rq[0] + rq[1] + rq[2] + rq[3];
  float mean = s * (1.f / 1024.f);
  float var  = q * (1.f / 1024.f) - mean * mean;
  float rstd = rsqrtf(var + 1e-5f);
  float4 wv = ((const float4*)w)[t];
  float4 bv = ((const float4*)b)[t];
  float4 y;
  y.x = (x.x - mean) * rstd * wv.x + bv.x;
  y.y = (x.y - mean) * rstd * wv.y + bv.y;
  y.z = (x.z - mean) * rstd * wv.z + bv.z;
  y.w = (x.w - mean) * rstd * wv.w + bv.w;
  if (outf) ((float4*)(outf + (size_t)row * 1024))[t] = y;
  ushort4 ub;
  ub.x = f2b(y.x); ub.y = f2b(y.y); ub.z = f2b(y.z); ub.w = f2b(y.w);
  ((ushort4*)(outb + (size_t)row * 1024))[t] = ub;
}

// ---------------------------------------------------------------------------
// prep_k: ALL weight transposes (fp32->bf16, [R][C]->[C][R]) + ln1 in ONE
// launch. id < 2816: transpose work (W1 | W2 | Wq/Wk/Wv); id >= 2816: ln1 row.
__global__ __launch_bounds__(256)
void prep_k(const float* __restrict__ W1, const float* __restrict__ W2,
            const float* __restrict__ Wq, const float* __restrict__ Wk,
            const float* __restrict__ Wv,
            u16* __restrict__ W1t, u16* __restrict__ W2t,
            u16* __restrict__ Wqkv_t,
            const float* __restrict__ emb, const float* __restrict__ ln1w,
            const float* __restrict__ ln1b,
            float* __restrict__ x, u16* __restrict__ xb) {
  __shared__ float tile[64][65];   // transpose path (16.6 KB)
  __shared__ float rs[4], rq[4];   // ln path
  int id = blockIdx.x;
  if (id >= 2816) {                // ----- ln1 path -----
    ln_body(id - 2816, emb, nullptr, ln1w, ln1b, x, xb, rs, rq);
    return;
  }
  // ----- transpose path (verified transpose_all_k body) -----
  const float* in; u16* out; int R, C, r0, c0;
  if (id < 1024) {
    in = W1; out = W1t; R = 1024; C = 4096;
    r0 = (id & 15) * 64; c0 = (id >> 4) * 64;
  } else if (id < 2048) {
    id -= 1024;
    in = W2; out = W2t; R = 4096; C = 1024;
    r0 = (id >> 4) * 64; c0 = (id & 15) * 64;
  } else {
    id -= 2048;                    // 0..767: 48 head-matrices x 16 row-chunks
    int z = id >> 4, which = z >> 4, sub = z & 15;
    const float* base = which == 0 ? Wq : (which == 1 ? Wk : Wv);
    in = base + (size_t)sub * 1024 * 64;
    out = Wqkv_t + (size_t)which * 1024 * 1024 + (size_t)sub * 64 * 1024;
    R = 1024; C = 64;
    r0 = (id & 15) * 64; c0 = 0;
  }
  int tr = threadIdx.x >> 6, tc = threadIdx.x & 63;
#pragma unroll
  for (int i = 0; i < 16; i++) {
    int r = i * 4 + tr;
    tile[r][tc] = in[(size_t)(r0 + r) * C + c0 + tc];
  }
  __syncthreads();
#pragma unroll
  for (int i = 0; i < 16; i++) {
    int c = i * 4 + tr;
    out[(size_t)(c0 + c) * R + r0 + tc] = f2b(tile[tc][c]);
  }
}

// ---------------------------------------------------------------------------
// ln_k: standalone LN (used for ln2 = LN(x + ob)).
__global__ __launch_bounds__(256)
void ln_k(const float* __restrict__ in, const float* __restrict__ in2,
          const float* __restrict__ w, const float* __restrict__ b,
          float* __restrict__ outf, u16* __restrict__ outb) {
  __shared__ float rs[4], rq[4];
  ln_body(blockIdx.x, in, in2, w, b, outf, outb, rs, rq);
}

// ---------------------------------------------------------------------------
// bf16 transpose for V: vin [bh][2048][64] -> vt [bh][64][2048]
__global__ __launch_bounds__(256)
void vtrans_k(const u16* __restrict__ vin, u16* __restrict__ vt) {
  __shared__ __align__(16) u16 tile[64][72];
  int s0 = blockIdx.x * 64, bh = blockIdx.y;
  const u16* ip = vin + (size_t)bh * 2048 * 64;
  u16* op = vt + (size_t)bh * 64 * 2048;
  int t = threadIdx.x;
#pragma unroll
  for (int i = 0; i < 2; i++) {
    int idx = i * 256 + t, r = idx >> 3, c = idx & 7;
    *(uint4*)&tile[r][c * 8] = *(const uint4*)(ip + (size_t)(s0 + r) * 64 + c * 8);
  }
  __syncthreads();
#pragma unroll
  for (int i = 0; i < 16; i++) {
    int d = i * 4 + (t >> 6), s = t & 63;
    op[(size_t)d * 2048 + s0 + s] = tile[s][d];
  }
}

// ---------------------------------------------------------------------------
// 128x128 tile bf16 GEMM body, BK=64, 256 threads (4 waves, 2x2 of 64x64).
// XOR chunk swizzle -> conflict-free ds_read_b128. blockIdx.z = split-K slice.
// 2-phase LDS dbuf: stage k+1 BEFORE compute k, ONE barrier per K-step so the
// vmcnt(0) drain lands after the MFMA cluster (latency hidden). [R8, verified]
#define EPI_QKV  0
#define EPI_RELU 1
#define EPI_RES  2

// 0.125 * log2(e): folds the 1/sqrt(64) score scale AND the exp->exp2
// conversion into the Q projection (attention uses exp2 directly).
#define QSCALE 0.18033688011112042f

template <int EPI>
__device__ __forceinline__
void gemm_body(const u16* __restrict__ A, const u16* __restrict__ Bt,
               int K, int lda, int ldbt,
               const float* __restrict__ bias0, const float* __restrict__ bias1,
               const float* __restrict__ bias2, const float* __restrict__ res,
               int ldout, u16* __restrict__ outb, float* __restrict__ outf,
               float* __restrict__ outp) {
  __shared__ __align__(16) u16 As[2][128 * 64];
  __shared__ __align__(16) u16 Bs[2][128 * 64];
  int t = threadIdx.x;
  int wave = t >> 6, lane = t & 63, quad = lane >> 4, l16 = lane & 15;
  int x7 = l16 & 7;
  int wm = (wave >> 1) * 64, wn = (wave & 1) * 64;
  int bm = blockIdx.x * 128, bn = blockIdx.y * 128;
  int zoff = blockIdx.z * K;

  const u16* Agl[4];
  const u16* Bgl[4];
#pragma unroll
  for (int i = 0; i < 4; i++) {
    int idx = i * 256 + t, r = idx >> 3, c = (idx & 7) ^ (r & 7);
    Agl[i] = A + (size_t)(bm + r) * lda + zoff + c * 8;
    Bgl[i] = Bt + (size_t)(bn + r) * ldbt + zoff + c * 8;
  }

  f32x4 acc[4][4] = {};

  // prologue: stage tile 0 into buffer 0
#pragma unroll
  for (int i = 0; i < 4; i++) {
    gload16(Agl[i], (u16*)As[0] + t * 8 + i * 2048);
    gload16(Bgl[i], (u16*)Bs[0] + t * 8 + i * 2048);
  }
  __syncthreads();

  int nk = K >> 6;
  for (int kt = 0; kt < nk; kt++) {
    const u16* Ac = As[kt & 1];
    const u16* Bc = Bs[kt & 1];
    if (kt + 1 < nk) {
      int k1 = (kt + 1) << 6;
      u16* An = (u16*)As[(kt + 1) & 1] + t * 8;
      u16* Bn = (u16*)Bs[(kt + 1) & 1] + t * 8;
#pragma unroll
      for (int i = 0; i < 4; i++) {
        gload16(Agl[i] + k1, An + i * 2048);
        gload16(Bgl[i] + k1, Bn + i * 2048);
      }
    }
#pragma unroll
    for (int kc = 0; kc < 2; kc++) {
      bf16x8 af[4], bfr[4];
#pragma unroll
      for (int i = 0; i < 4; i++) {
        int r = wm + i * 16 + l16;
        af[i] = *(const bf16x8*)(Ac + r * 64 + (((kc * 4 + quad) ^ x7) * 8));
      }
#pragma unroll
      for (int j = 0; j < 4; j++) {
        int r = wn + j * 16 + l16;
        bfr[j] = *(const bf16x8*)(Bc + r * 64 + (((kc * 4 + quad) ^ x7) * 8));
      }
#pragma unroll
      for (int i = 0; i < 4; i++)
#pragma unroll
        for (int j = 0; j < 4; j++)
          acc[i][j] = __builtin_amdgcn_mfma_f32_16x16x32_bf16(af[i], bfr[j],
                                                              acc[i][j], 0, 0, 0);
    }
    // one barrier per K-step: waits (a) all waves done reading cur buffer,
    // (b) vmcnt(0) drain of next-tile global_load_lds -- after the MFMAs.
    __syncthreads();
  }

#pragma unroll
  for (int i = 0; i < 4; i++) {
#pragma unroll
    for (int j = 0; j < 4; j++) {
      int c = bn + wn + j * 16 + l16;
#pragma unroll
      for (int rr = 0; rr < 4; rr++) {
        int r = bm + wm + i * 16 + quad * 4 + rr;
        float v = acc[i][j][rr];
        if (EPI == EPI_QKV) {
          int which = c >> 10, h = (c >> 6) & 15, d = c & 63;
          const float* bp = which == 0 ? bias0 : (which == 1 ? bias1 : bias2);
          v += bp[h * 64 + d];
          if (which == 0) v *= QSCALE;  // prescale Q for base-2 softmax
          int bb = r >> 11, ss = r & 2047;
          outb[((size_t)(which * 32 + bb * 16 + h) * 2048 + ss) * 64 + d] = f2b(v);
        } else if (EPI == EPI_RELU) {
          v += bias0[c];
          v = v > 0.f ? v : 0.f;
          outb[(size_t)r * ldout + c] = f2b(v);
        } else {
          if (blockIdx.z == 0) {
            v += bias0[c] + res[(size_t)r * ldout + c];
            outf[(size_t)r * ldout + c] = v;
          } else {
            outp[(size_t)r * ldout + c] = v;
          }
        }
      }
    }
  }
}

__global__ __launch_bounds__(256)
void qkv_gemm(const u16* A, const u16* Bt, int K, int lda, int ldbt,
              const float* b0, const float* b1, const float* b2,
              u16* outb) {
  gemm_body<EPI_QKV>(A, Bt, K, lda, ldbt, b0, b1, b2, nullptr, 0, outb, nullptr, nullptr);
}
__global__ __launch_bounds__(256)
void ffn1_gemm(const u16* A, const u16* Bt, int K, int lda, int ldbt,
               const float* b0, int ldout, u16* outb) {
  gemm_body<EPI_RELU>(A, Bt, K, lda, ldbt, b0, nullptr, nullptr, nullptr, ldout, outb, nullptr, nullptr);
}
__global__ __launch_bounds__(256)
void ffn2_gemm(const u16* A, const u16* Bt, int K, int lda, int ldbt,
               const float* b0, const float* res, int ldout,
               float* outf, float* outp) {
  gemm_body<EPI_RES>(A, Bt, K, lda, ldbt, b0, nullptr, nullptr, res, ldout, nullptr, outf, outp);
}

// out[i] += part[i]  (fp32, float4)
__global__ __launch_bounds__(256)
void reduce_k(float* __restrict__ out, const float* __restrict__ part) {
  int i = blockIdx.x * 256 + threadIdx.x;
  float4 a = ((const float4*)part)[i];
  float4 b = ((float4*)out)[i];
  b.x += a.x; b.y += a.y; b.z += a.z; b.w += a.w;
  ((float4*)out)[i] = b;
}

// ---------------------------------------------------------------------------
// Flash attention v5, causal. Grid (16, 32), 512 threads (8 waves).
// LDS-staged K/V dbuf, 1 barrier/iter, S^T orientation, 2-shuffle softmax rows,
// raw v_exp_f32, v_perm P-pack, alpha broadcast via per-wave LDS aux. [verified]
__global__ __launch_bounds__(512, 6)
void attn_k(const u16* __restrict__ qkv, const u16* __restrict__ vt,
            float* __restrict__ o) {
  int bh = blockIdx.y, b = bh >> 4, h = bh & 15;
  int Qt = b ? (15 - (int)blockIdx.x) : (int)blockIdx.x;  // causal balance
  int t = threadIdx.x;
  int wave = t >> 6, lane = t & 63, quad = lane >> 4, l16 = lane & 15;
  int x7 = l16 & 7;
  int q0 = Qt * 128 + wave * 16;

  const u16* qg = qkv + (size_t)bh * (2048 * 64);
  const u16* kg = qkv + (size_t)(32 + bh) * (2048 * 64);
  const u16* vg = vt + (size_t)bh * (64 * 2048);  // [dh][s]

  __shared__ __align__(16) u16 Ks[2][64 * 64];
  __shared__ __align__(16) u16 Vs[2][64 * 64];
  __shared__ __align__(16) u16 Ps[8][16 * 64 + 32];  // +64B aux per wave
  u16* Pw = Ps[wave];
  float* auxf = (float*)(Pw + 1024);

  int sr = t >> 3, sc_ = (t & 7) ^ (sr & 7);

  gload16(kg + (size_t)sr * 64 + sc_ * 8, Ks[0] + t * 8);
  gload16(vg + (size_t)sr * 2048 + sc_ * 8, Vs[0] + t * 8);

  bf16x8 qf0 = ld16(qg + (size_t)(q0 + l16) * 64 + quad * 8);
  bf16x8 qf1 = ld16(qg + (size_t)(q0 + l16) * 64 + 32 + quad * 8);

  f32x4 oacc[4] = {};
  float mo = NEG_INF, ll = 0.f;
  int kmax_w = q0 >> 6;
  int klast = 2 * Qt + 1;

  __syncthreads();

  for (int kt = 0; kt <= klast; kt++) {
    const u16* ks = Ks[kt & 1];
    const u16* vs = Vs[kt & 1];
    if (kt < klast) {
      gload16(kg + (size_t)((kt + 1) * 64 + sr) * 64 + sc_ * 8, Ks[(kt + 1) & 1] + t * 8);
      gload16(vg + (size_t)sr * 2048 + (kt + 1) * 64 + sc_ * 8, Vs[(kt + 1) & 1] + t * 8);
    }
    if (kt <= kmax_w) {
      // ---- S^T: A = K rows (m = kv), B = Q rows (n = q) ----
      f32x4 sc[4];
#pragma unroll
      for (int g = 0; g < 4; g++) {
        const u16* kr = ks + (g * 16 + l16) * 64;
        bf16x8 kf0 = *(const bf16x8*)(kr + ((quad ^ x7) * 8));
        bf16x8 kf1 = *(const bf16x8*)(kr + (((4 + quad) ^ x7) * 8));
        f32x4 s = {};
        s = __builtin_amdgcn_mfma_f32_16x16x32_bf16(kf0, qf0, s, 0, 0, 0);
        s = __builtin_amdgcn_mfma_f32_16x16x32_bf16(kf1, qf1, s, 0, 0, 0);
        sc[g] = s;
      }

      if (kt == kmax_w) {  // diagonal tile: mask kv > q
#pragma unroll
        for (int g = 0; g < 4; g++) {
          int kvb = kt * 64 + g * 16 + quad * 4;
#pragma unroll
          for (int rr = 0; rr < 4; rr++)
            if (kvb + rr > q0 + l16) sc[g][rr] = NEG_INF;
        }
      }

      // ---- online softmax, row = q = l16 ----
      float mx = sc[0][0];
#pragma unroll
      for (int g = 0; g < 4; g++)
#pragma unroll
        for (int rr = 0; rr < 4; rr++) mx = fmaxf(mx, sc[g][rr]);
      mx = fmaxf(mx, __shfl_xor(mx, 16));
      mx = fmaxf(mx, __shfl_xor(mx, 32));
      float mnew = fmaxf(mo, mx);
      float al = EXP2F(mo - mnew);
      mo = mnew;

      float sum = 0.f;
#pragma unroll
      for (int g = 0; g < 4; g++) {
        float p0 = EXP2F(sc[g][0] - mnew);
        float p1 = EXP2F(sc[g][1] - mnew);
        float p2 = EXP2F(sc[g][2] - mnew);
        float p3 = EXP2F(sc[g][3] - mnew);
        sum += (p0 + p1) + (p2 + p3);
        u32 lo = pack_bf16_trunc(p0, p1);
        u32 hi = pack_bf16_trunc(p2, p3);
        int slot = (2 * g + (quad >> 1)) ^ x7;
        *(uint2*)(Pw + l16 * 64 + slot * 8 + (quad & 1) * 4) = make_uint2(lo, hi);
      }
      sum += __shfl_xor(sum, 16);
      sum += __shfl_xor(sum, 32);
      ll = ll * al + sum;

      // rescale O: alpha indexed by q=l16 -> broadcast via per-wave LDS aux
      if (lane < 16) auxf[lane] = al;
      f32x4 av = *(const f32x4*)(auxf + quad * 4);
#pragma unroll
      for (int g = 0; g < 4; g++)
#pragma unroll
        for (int rr = 0; rr < 4; rr++) oacc[g][rr] *= av[rr];

      // ---- O += P(A) x V^T(B) ----
      bf16x8 pf0 = *(const bf16x8*)(Pw + l16 * 64 + ((quad ^ x7) * 8));
      bf16x8 pf1 = *(const bf16x8*)(Pw + l16 * 64 + (((4 + quad) ^ x7) * 8));
#pragma unroll
      for (int g = 0; g < 4; g++) {
        const u16* vr = vs + (g * 16 + l16) * 64;
        bf16x8 vf0 = *(const bf16x8*)(vr + ((quad ^ x7) * 8));
        bf16x8 vf1 = *(const bf16x8*)(vr + (((4 + quad) ^ x7) * 8));
        oacc[g] = __builtin_amdgcn_mfma_f32_16x16x32_bf16(pf0, vf0, oacc[g], 0, 0, 0);
        oacc[g] = __builtin_amdgcn_mfma_f32_16x16x32_bf16(pf1, vf1, oacc[g], 0, 0, 0);
      }
    }
    __syncthreads();
  }

  // epilogue: O row = m = quad*4+rr, col = dh = g*16+l16; l indexed by l16
  if (lane < 16) auxf[lane] = ll;
  f32x4 lv = *(const f32x4*)(auxf + quad * 4);
  float rinv[4];
#pragma unroll
  for (int rr = 0; rr < 4; rr++) rinv[rr] = 1.f / lv[rr];
  float* op = o + ((size_t)b * 2048 + q0) * 1024 + h * 64;
#pragma unroll
  for (int g = 0; g < 4; g++)
#pragma unroll
    for (int rr = 0; rr < 4; rr++)
      op[(size_t)(quad * 4 + rr) * 1024 + g * 16 + l16] = oacc[g][rr] * rinv[rr];
}

// ---------------------------------------------------------------------------
extern "C" void kernel_launch(void* const* d_in, const int* in_sizes, int n_in,
                              void* d_out, int out_size, void* d_ws, size_t ws_size,
                              hipStream_t stream) {
  const float* emb  = (const float*)d_in[0];
  const float* Wq   = (const float*)d_in[1];
  const float* bq   = (const float*)d_in[2];
  const float* Wk   = (const float*)d_in[3];
  const float* bk   = (const float*)d_in[4];
  const float* Wv   = (const float*)d_in[5];
  const float* bv   = (const float*)d_in[6];
  const float* ln1w = (const float*)d_in[7];
  const float* ln1b = (const float*)d_in[8];
  const float* ln2w = (const float*)d_in[9];
  const float* ln2b = (const float*)d_in[10];
  const float* W1   = (const float*)d_in[11];
  const float* b1   = (const float*)d_in[12];
  const float* W2   = (const float*)d_in[13];
  const float* b2   = (const float*)d_in[14];
  float* out = (float*)d_out;

  char* p = (char*)d_ws;
  u16*   Wqkv_t = (u16*)p;   p += (size_t)3072 * 1024 * 2;
  u16*   W1t    = (u16*)p;   p += (size_t)4096 * 1024 * 2;
  u16*   W2t    = (u16*)p;   p += (size_t)1024 * 4096 * 2;
  float* x      = (float*)p; p += (size_t)4096 * 1024 * 4;
  u16*   xb     = (u16*)p;   p += (size_t)4096 * 1024 * 2;
  u16*   qkvb   = (u16*)p;   p += (size_t)3 * 32 * 2048 * 64 * 2;  // 25.2 MB
  float* ob     = (float*)p; p += (size_t)4096 * 1024 * 4;         // 16.8 MB
  float* y      = (float*)p; p += (size_t)4096 * 1024 * 4;
  u16*   yb     = (u16*)p;   p += (size_t)4096 * 1024 * 2;
  u16*   hb     = (u16*)qkvb; // alias: qkvb+ob (42 MB) dead before FFN1 writes hb (33.6 MB)
  u16*   vT     = (u16*)y;    // alias: vT (8.4 MB) dead before ln2 writes y
  float* part   = x;          // alias: x (16.8 MB fp32) dead before FFN2 z=1 partial
  if (ws_size < (size_t)(p - (char*)d_ws)) return;

  // fused: all weight transposes (2816 blocks) + ln1 (4096 blocks)
  prep_k<<<dim3(2816 + 4096), 256, 0, stream>>>(
      W1, W2, Wq, Wk, Wv, W1t, W2t, Wqkv_t, emb, ln1w, ln1b, x, xb);

  qkv_gemm<<<dim3(32, 24, 1), 256, 0, stream>>>(
      xb, Wqkv_t, 1024, 1024, 1024, bq, bk, bv, qkvb);

  vtrans_k<<<dim3(32, 32), 256, 0, stream>>>(qkvb + (size_t)64 * 2048 * 64, vT);

  attn_k<<<dim3(16, 32), 512, 0, stream>>>(qkvb, vT, ob);

  ln_k<<<dim3(4096), 256, 0, stream>>>(x, ob, ln2w, ln2b, y, yb);

  ffn1_gemm<<<dim3(32, 32, 1), 256, 0, stream>>>(
      yb, W1t, 1024, 1024, 1024, b1, 4096, hb);

  // FFN2 split-K=2: z=0 -> out (+b2+y), z=1 -> raw partial into `part`
  ffn2_gemm<<<dim3(32, 8, 2), 256, 0, stream>>>(
      hb, W2t, 2048, 4096, 4096, b2, y, 1024, out, part);

  reduce_k<<<dim3(4096), 256, 0, stream>>>(out, part);
}

// Round 11
// 324.128 us; speedup vs baseline: 1.0302x; 1.0023x over previous
//
#include <hip/hip_runtime.h>

// TransformerLayer on MI355X (gfx950), bf16 MFMA pipeline, fp32 LN/softmax/accum.
// R17 == R16 (session best, 324.9us verified). FINAL STATE.
// - prep_k: all weight transposes + ln1 fused (launch-count 9 -> 8).
// - GEMMs: 128x128/BK=64 2-phase LDS dbuf (stage-next -> MFMA -> one barrier),
//   2 blocks/CU, chunk-XOR swizzle (bank-conflict 0). Structure ceiling ~625TF;
//   escapes tested & closed: R7 splitK4 (-), R9-R11 8-phase x3 (-), R13
//   256-tile@2ph (-).
// - attn: R5-lineage flash attn (S^T orientation, LDS K/V dbuf, in-register
//   softmax, v_perm P-pack, LDS-aux alpha bcast). R14 setprio/defer-max were
//   net-negative here (lockstep 8-wave blocks = m190 regime) -- excluded.
// - ln/vtrans/reduce: vectorized, coalesced, at BW.

typedef unsigned short u16;
typedef unsigned int   u32;
typedef __bf16 bf16x8 __attribute__((ext_vector_type(8)));
typedef float  f32x4  __attribute__((ext_vector_type(4)));

#define NEG_INF (-__builtin_inff())

#if __has_builtin(__builtin_amdgcn_exp2f)
#define EXP2F(x) __builtin_amdgcn_exp2f(x)
#else
#define EXP2F(x) exp2f(x)
#endif

// pack: result = lo16:=a.hi16, hi16:=b.hi16 (trunc bf16 pair)
__device__ __forceinline__ u32 pack_bf16_trunc(float a, float b) {
#if __has_builtin(__builtin_amdgcn_perm)
  return __builtin_amdgcn_perm(__float_as_uint(b), __float_as_uint(a), 0x07060302u);
#else
  return (__float_as_uint(a) >> 16) | (__float_as_uint(b) & 0xFFFF0000u);
#endif
}

// fp32 -> bf16 RNE (finite inputs only)
__device__ __forceinline__ u16 f2b(float f) {
  u32 u = __float_as_uint(f);
  u = (u + 0x7fffu + ((u >> 16) & 1u)) >> 16;
  return (u16)u;
}

// async global->LDS, 16B per lane. LDS dest must be wave-uniform base + lane*16.
__device__ __forceinline__ void gload16(const void* g, void* l) {
  __builtin_amdgcn_global_load_lds(
      (const __attribute__((address_space(1))) u32*)g,
      (__attribute__((address_space(3))) u32*)l, 16, 0, 0);
}

__device__ __forceinline__ bf16x8 ld16(const u16* p) { return *(const bf16x8*)p; }

// ---------------------------------------------------------------------------
// LN body (verified ln_k), shared by prep_k (ln1) and ln_k (ln2).
__device__ __forceinline__
void ln_body(int row, const float* __restrict__ in, const float* __restrict__ in2,
             const float* __restrict__ w, const float* __restrict__ b,
             float* __restrict__ outf, u16* __restrict__ outb,
             float* rs, float* rq) {
  int t = threadIdx.x;
  const float4* ip = (const float4*)(in + (size_t)row * 1024);
  float4 x = ip[t];
  if (in2) {
    const float4* ip2 = (const float4*)(in2 + (size_t)row * 1024);
    float4 o = ip2[t];
    x.x += o.x; x.y += o.y; x.z += o.z; x.w += o.w;
  }
  float s = x.x + x.y + x.z + x.w;
  float q = x.x * x.x + x.y * x.y + x.z * x.z + x.w * x.w;
#pragma unroll
  for (int m = 32; m; m >>= 1) { s += __shfl_xor(s, m); q += __shfl_xor(q, m); }
  if ((t & 63) == 0) { rs[t >> 6] = s; rq[t >> 6] = q; }
  __syncthreads();
  s = rs[0] + rs[1] + rs[2] + rs[3];
  q = rq[0] + rq[1] + rq[2] + rq[3];
  float mean = s * (1.f / 1024.f);
  float var  = q * (1.f / 1024.f) - mean * mean;
  float rstd = rsqrtf(var + 1e-5f);
  float4 wv = ((const float4*)w)[t];
  float4 bv = ((const float4*)b)[t];
  float4 y;
  y.x = (x.x - mean) * rstd * wv.x + bv.x;
  y.y = (x.y - mean) * rstd * wv.y + bv.y;
  y.z = (x.z - mean) * rstd * wv.z + bv.z;
  y.w = (x.w - mean) * rstd * wv.w + bv.w;
  if (outf) ((float4*)(outf + (size_t)row * 1024))[t] = y;
  ushort4 ub;
  ub.x = f2b(y.x); ub.y = f2b(y.y); ub.z = f2b(y.z); ub.w = f2b(y.w);
  ((ushort4*)(outb + (size_t)row * 1024))[t] = ub;
}

// ---------------------------------------------------------------------------
// prep_k: ALL weight transposes (fp32->bf16, [R][C]->[C][R]) + ln1 in ONE
// launch. id < 2816: transpose work (W1 | W2 | Wq/Wk/Wv); id >= 2816: ln1 row.
__global__ __launch_bounds__(256)
void prep_k(const float* __restrict__ W1, const float* __restrict__ W2,
            const float* __restrict__ Wq, const float* __restrict__ Wk,
            const float* __restrict__ Wv,
            u16* __restrict__ W1t, u16* __restrict__ W2t,
            u16* __restrict__ Wqkv_t,
            const float* __restrict__ emb, const float* __restrict__ ln1w,
            const float* __restrict__ ln1b,
            float* __restrict__ x, u16* __restrict__ xb) {
  __shared__ float tile[64][65];   // transpose path (16.6 KB)
  __shared__ float rs[4], rq[4];   // ln path
  int id = blockIdx.x;
  if (id >= 2816) {                // ----- ln1 path -----
    ln_body(id - 2816, emb, nullptr, ln1w, ln1b, x, xb, rs, rq);
    return;
  }
  // ----- transpose path (verified transpose_all_k body) -----
  const float* in; u16* out; int R, C, r0, c0;
  if (id < 1024) {
    in = W1; out = W1t; R = 1024; C = 4096;
    r0 = (id & 15) * 64; c0 = (id >> 4) * 64;
  } else if (id < 2048) {
    id -= 1024;
    in = W2; out = W2t; R = 4096; C = 1024;
    r0 = (id >> 4) * 64; c0 = (id & 15) * 64;
  } else {
    id -= 2048;                    // 0..767: 48 head-matrices x 16 row-chunks
    int z = id >> 4, which = z >> 4, sub = z & 15;
    const float* base = which == 0 ? Wq : (which == 1 ? Wk : Wv);
    in = base + (size_t)sub * 1024 * 64;
    out = Wqkv_t + (size_t)which * 1024 * 1024 + (size_t)sub * 64 * 1024;
    R = 1024; C = 64;
    r0 = (id & 15) * 64; c0 = 0;
  }
  int tr = threadIdx.x >> 6, tc = threadIdx.x & 63;
#pragma unroll
  for (int i = 0; i < 16; i++) {
    int r = i * 4 + tr;
    tile[r][tc] = in[(size_t)(r0 + r) * C + c0 + tc];
  }
  __syncthreads();
#pragma unroll
  for (int i = 0; i < 16; i++) {
    int c = i * 4 + tr;
    out[(size_t)(c0 + c) * R + r0 + tc] = f2b(tile[tc][c]);
  }
}

// ---------------------------------------------------------------------------
// ln_k: standalone LN (used for ln2 = LN(x + ob)).
__global__ __launch_bounds__(256)
void ln_k(const float* __restrict__ in, const float* __restrict__ in2,
          const float* __restrict__ w, const float* __restrict__ b,
          float* __restrict__ outf, u16* __restrict__ outb) {
  __shared__ float rs[4], rq[4];
  ln_body(blockIdx.x, in, in2, w, b, outf, outb, rs, rq);
}

// ---------------------------------------------------------------------------
// bf16 transpose for V: vin [bh][2048][64] -> vt [bh][64][2048]
__global__ __launch_bounds__(256)
void vtrans_k(const u16* __restrict__ vin, u16* __restrict__ vt) {
  __shared__ __align__(16) u16 tile[64][72];
  int s0 = blockIdx.x * 64, bh = blockIdx.y;
  const u16* ip = vin + (size_t)bh * 2048 * 64;
  u16* op = vt + (size_t)bh * 64 * 2048;
  int t = threadIdx.x;
#pragma unroll
  for (int i = 0; i < 2; i++) {
    int idx = i * 256 + t, r = idx >> 3, c = idx & 7;
    *(uint4*)&tile[r][c * 8] = *(const uint4*)(ip + (size_t)(s0 + r) * 64 + c * 8);
  }
  __syncthreads();
#pragma unroll
  for (int i = 0; i < 16; i++) {
    int d = i * 4 + (t >> 6), s = t & 63;
    op[(size_t)d * 2048 + s0 + s] = tile[s][d];
  }
}

// ---------------------------------------------------------------------------
// 128x128 tile bf16 GEMM body, BK=64, 256 threads (4 waves, 2x2 of 64x64).
// XOR chunk swizzle -> conflict-free ds_read_b128. blockIdx.z = split-K slice.
// 2-phase LDS dbuf: stage k+1 BEFORE compute k, ONE barrier per K-step so the
// vmcnt(0) drain lands after the MFMA cluster (latency hidden). [R8, verified]
#define EPI_QKV  0
#define EPI_RELU 1
#define EPI_RES  2

// 0.125 * log2(e): folds the 1/sqrt(64) score scale AND the exp->exp2
// conversion into the Q projection (attention uses exp2 directly).
#define QSCALE 0.18033688011112042f

template <int EPI>
__device__ __forceinline__
void gemm_body(const u16* __restrict__ A, const u16* __restrict__ Bt,
               int K, int lda, int ldbt,
               const float* __restrict__ bias0, const float* __restrict__ bias1,
               const float* __restrict__ bias2, const float* __restrict__ res,
               int ldout, u16* __restrict__ outb, float* __restrict__ outf,
               float* __restrict__ outp) {
  __shared__ __align__(16) u16 As[2][128 * 64];
  __shared__ __align__(16) u16 Bs[2][128 * 64];
  int t = threadIdx.x;
  int wave = t >> 6, lane = t & 63, quad = lane >> 4, l16 = lane & 15;
  int x7 = l16 & 7;
  int wm = (wave >> 1) * 64, wn = (wave & 1) * 64;
  int bm = blockIdx.x * 128, bn = blockIdx.y * 128;
  int zoff = blockIdx.z * K;

  const u16* Agl[4];
  const u16* Bgl[4];
#pragma unroll
  for (int i = 0; i < 4; i++) {
    int idx = i * 256 + t, r = idx >> 3, c = (idx & 7) ^ (r & 7);
    Agl[i] = A + (size_t)(bm + r) * lda + zoff + c * 8;
    Bgl[i] = Bt + (size_t)(bn + r) * ldbt + zoff + c * 8;
  }

  f32x4 acc[4][4] = {};

  // prologue: stage tile 0 into buffer 0
#pragma unroll
  for (int i = 0; i < 4; i++) {
    gload16(Agl[i], (u16*)As[0] + t * 8 + i * 2048);
    gload16(Bgl[i], (u16*)Bs[0] + t * 8 + i * 2048);
  }
  __syncthreads();

  int nk = K >> 6;
  for (int kt = 0; kt < nk; kt++) {
    const u16* Ac = As[kt & 1];
    const u16* Bc = Bs[kt & 1];
    if (kt + 1 < nk) {
      int k1 = (kt + 1) << 6;
      u16* An = (u16*)As[(kt + 1) & 1] + t * 8;
      u16* Bn = (u16*)Bs[(kt + 1) & 1] + t * 8;
#pragma unroll
      for (int i = 0; i < 4; i++) {
        gload16(Agl[i] + k1, An + i * 2048);
        gload16(Bgl[i] + k1, Bn + i * 2048);
      }
    }
#pragma unroll
    for (int kc = 0; kc < 2; kc++) {
      bf16x8 af[4], bfr[4];
#pragma unroll
      for (int i = 0; i < 4; i++) {
        int r = wm + i * 16 + l16;
        af[i] = *(const bf16x8*)(Ac + r * 64 + (((kc * 4 + quad) ^ x7) * 8));
      }
#pragma unroll
      for (int j = 0; j < 4; j++) {
        int r = wn + j * 16 + l16;
        bfr[j] = *(const bf16x8*)(Bc + r * 64 + (((kc * 4 + quad) ^ x7) * 8));
      }
#pragma unroll
      for (int i = 0; i < 4; i++)
#pragma unroll
        for (int j = 0; j < 4; j++)
          acc[i][j] = __builtin_amdgcn_mfma_f32_16x16x32_bf16(af[i], bfr[j],
                                                              acc[i][j], 0, 0, 0);
    }
    // one barrier per K-step: waits (a) all waves done reading cur buffer,
    // (b) vmcnt(0) drain of next-tile global_load_lds -- after the MFMAs.
    __syncthreads();
  }

#pragma unroll
  for (int i = 0; i < 4; i++) {
#pragma unroll
    for (int j = 0; j < 4; j++) {
      int c = bn + wn + j * 16 + l16;
#pragma unroll
      for (int rr = 0; rr < 4; rr++) {
        int r = bm + wm + i * 16 + quad * 4 + rr;
        float v = acc[i][j][rr];
        if (EPI == EPI_QKV) {
          int which = c >> 10, h = (c >> 6) & 15, d = c & 63;
          const float* bp = which == 0 ? bias0 : (which == 1 ? bias1 : bias2);
          v += bp[h * 64 + d];
          if (which == 0) v *= QSCALE;  // prescale Q for base-2 softmax
          int bb = r >> 11, ss = r & 2047;
          outb[((size_t)(which * 32 + bb * 16 + h) * 2048 + ss) * 64 + d] = f2b(v);
        } else if (EPI == EPI_RELU) {
          v += bias0[c];
          v = v > 0.f ? v : 0.f;
          outb[(size_t)r * ldout + c] = f2b(v);
        } else {
          if (blockIdx.z == 0) {
            v += bias0[c] + res[(size_t)r * ldout + c];
            outf[(size_t)r * ldout + c] = v;
          } else {
            outp[(size_t)r * ldout + c] = v;
          }
        }
      }
    }
  }
}

__global__ __launch_bounds__(256)
void qkv_gemm(const u16* A, const u16* Bt, int K, int lda, int ldbt,
              const float* b0, const float* b1, const float* b2,
              u16* outb) {
  gemm_body<EPI_QKV>(A, Bt, K, lda, ldbt, b0, b1, b2, nullptr, 0, outb, nullptr, nullptr);
}
__global__ __launch_bounds__(256)
void ffn1_gemm(const u16* A, const u16* Bt, int K, int lda, int ldbt,
               const float* b0, int ldout, u16* outb) {
  gemm_body<EPI_RELU>(A, Bt, K, lda, ldbt, b0, nullptr, nullptr, nullptr, ldout, outb, nullptr, nullptr);
}
__global__ __launch_bounds__(256)
void ffn2_gemm(const u16* A, const u16* Bt, int K, int lda, int ldbt,
               const float* b0, const float* res, int ldout,
               float* outf, float* outp) {
  gemm_body<EPI_RES>(A, Bt, K, lda, ldbt, b0, nullptr, nullptr, res, ldout, nullptr, outf, outp);
}

// out[i] += part[i]  (fp32, float4)
__global__ __launch_bounds__(256)
void reduce_k(float* __restrict__ out, const float* __restrict__ part) {
  int i = blockIdx.x * 256 + threadIdx.x;
  float4 a = ((const float4*)part)[i];
  float4 b = ((float4*)out)[i];
  b.x += a.x; b.y += a.y; b.z += a.z; b.w += a.w;
  ((float4*)out)[i] = b;
}

// ---------------------------------------------------------------------------
// Flash attention v5, causal. Grid (16, 32), 512 threads (8 waves).
// LDS-staged K/V dbuf, 1 barrier/iter, S^T orientation, 2-shuffle softmax rows,
// raw v_exp_f32, v_perm P-pack, alpha broadcast via per-wave LDS aux. [verified]
__global__ __launch_bounds__(512, 6)
void attn_k(const u16* __restrict__ qkv, const u16* __restrict__ vt,
            float* __restrict__ o) {
  int bh = blockIdx.y, b = bh >> 4, h = bh & 15;
  int Qt = b ? (15 - (int)blockIdx.x) : (int)blockIdx.x;  // causal balance
  int t = threadIdx.x;
  int wave = t >> 6, lane = t & 63, quad = lane >> 4, l16 = lane & 15;
  int x7 = l16 & 7;
  int q0 = Qt * 128 + wave * 16;

  const u16* qg = qkv + (size_t)bh * (2048 * 64);
  const u16* kg = qkv + (size_t)(32 + bh) * (2048 * 64);
  const u16* vg = vt + (size_t)bh * (64 * 2048);  // [dh][s]

  __shared__ __align__(16) u16 Ks[2][64 * 64];
  __shared__ __align__(16) u16 Vs[2][64 * 64];
  __shared__ __align__(16) u16 Ps[8][16 * 64 + 32];  // +64B aux per wave
  u16* Pw = Ps[wave];
  float* auxf = (float*)(Pw + 1024);

  int sr = t >> 3, sc_ = (t & 7) ^ (sr & 7);

  gload16(kg + (size_t)sr * 64 + sc_ * 8, Ks[0] + t * 8);
  gload16(vg + (size_t)sr * 2048 + sc_ * 8, Vs[0] + t * 8);

  bf16x8 qf0 = ld16(qg + (size_t)(q0 + l16) * 64 + quad * 8);
  bf16x8 qf1 = ld16(qg + (size_t)(q0 + l16) * 64 + 32 + quad * 8);

  f32x4 oacc[4] = {};
  float mo = NEG_INF, ll = 0.f;
  int kmax_w = q0 >> 6;
  int klast = 2 * Qt + 1;

  __syncthreads();

  for (int kt = 0; kt <= klast; kt++) {
    const u16* ks = Ks[kt & 1];
    const u16* vs = Vs[kt & 1];
    if (kt < klast) {
      gload16(kg + (size_t)((kt + 1) * 64 + sr) * 64 + sc_ * 8, Ks[(kt + 1) & 1] + t * 8);
      gload16(vg + (size_t)sr * 2048 + (kt + 1) * 64 + sc_ * 8, Vs[(kt + 1) & 1] + t * 8);
    }
    if (kt <= kmax_w) {
      // ---- S^T: A = K rows (m = kv), B = Q rows (n = q) ----
      f32x4 sc[4];
#pragma unroll
      for (int g = 0; g < 4; g++) {
        const u16* kr = ks + (g * 16 + l16) * 64;
        bf16x8 kf0 = *(const bf16x8*)(kr + ((quad ^ x7) * 8));
        bf16x8 kf1 = *(const bf16x8*)(kr + (((4 + quad) ^ x7) * 8));
        f32x4 s = {};
        s = __builtin_amdgcn_mfma_f32_16x16x32_bf16(kf0, qf0, s, 0, 0, 0);
        s = __builtin_amdgcn_mfma_f32_16x16x32_bf16(kf1, qf1, s, 0, 0, 0);
        sc[g] = s;
      }

      if (kt == kmax_w) {  // diagonal tile: mask kv > q
#pragma unroll
        for (int g = 0; g < 4; g++) {
          int kvb = kt * 64 + g * 16 + quad * 4;
#pragma unroll
          for (int rr = 0; rr < 4; rr++)
            if (kvb + rr > q0 + l16) sc[g][rr] = NEG_INF;
        }
      }

      // ---- online softmax, row = q = l16 ----
      float mx = sc[0][0];
#pragma unroll
      for (int g = 0; g < 4; g++)
#pragma unroll
        for (int rr = 0; rr < 4; rr++) mx = fmaxf(mx, sc[g][rr]);
      mx = fmaxf(mx, __shfl_xor(mx, 16));
      mx = fmaxf(mx, __shfl_xor(mx, 32));
      float mnew = fmaxf(mo, mx);
      float al = EXP2F(mo - mnew);
      mo = mnew;

      float sum = 0.f;
#pragma unroll
      for (int g = 0; g < 4; g++) {
        float p0 = EXP2F(sc[g][0] - mnew);
        float p1 = EXP2F(sc[g][1] - mnew);
        float p2 = EXP2F(sc[g][2] - mnew);
        float p3 = EXP2F(sc[g][3] - mnew);
        sum += (p0 + p1) + (p2 + p3);
        u32 lo = pack_bf16_trunc(p0, p1);
        u32 hi = pack_bf16_trunc(p2, p3);
        int slot = (2 * g + (quad >> 1)) ^ x7;
        *(uint2*)(Pw + l16 * 64 + slot * 8 + (quad & 1) * 4) = make_uint2(lo, hi);
      }
      sum += __shfl_xor(sum, 16);
      sum += __shfl_xor(sum, 32);
      ll = ll * al + sum;

      // rescale O: alpha indexed by q=l16 -> broadcast via per-wave LDS aux
      if (lane < 16) auxf[lane] = al;
      f32x4 av = *(const f32x4*)(auxf + quad * 4);
#pragma unroll
      for (int g = 0; g < 4; g++)
#pragma unroll
        for (int rr = 0; rr < 4; rr++) oacc[g][rr] *= av[rr];

      // ---- O += P(A) x V^T(B) ----
      bf16x8 pf0 = *(const bf16x8*)(Pw + l16 * 64 + ((quad ^ x7) * 8));
      bf16x8 pf1 = *(const bf16x8*)(Pw + l16 * 64 + (((4 + quad) ^ x7) * 8));
#pragma unroll
      for (int g = 0; g < 4; g++) {
        const u16* vr = vs + (g * 16 + l16) * 64;
        bf16x8 vf0 = *(const bf16x8*)(vr + ((quad ^ x7) * 8));
        bf16x8 vf1 = *(const bf16x8*)(vr + (((4 + quad) ^ x7) * 8));
        oacc[g] = __builtin_amdgcn_mfma_f32_16x16x32_bf16(pf0, vf0, oacc[g], 0, 0, 0);
        oacc[g] = __builtin_amdgcn_mfma_f32_16x16x32_bf16(pf1, vf1, oacc[g], 0, 0, 0);
      }
    }
    __syncthreads();
  }

  // epilogue: O row = m = quad*4+rr, col = dh = g*16+l16; l indexed by l16
  if (lane < 16) auxf[lane] = ll;
  f32x4 lv = *(const f32x4*)(auxf + quad * 4);
  float rinv[4];
#pragma unroll
  for (int rr = 0; rr < 4; rr++) rinv[rr] = 1.f / lv[rr];
  float* op = o + ((size_t)b * 2048 + q0) * 1024 + h * 64;
#pragma unroll
  for (int g = 0; g < 4; g++)
#pragma unroll
    for (int rr = 0; rr < 4; rr++)
      op[(size_t)(quad * 4 + rr) * 1024 + g * 16 + l16] = oacc[g][rr] * rinv[rr];
}

// ---------------------------------------------------------------------------
extern "C" void kernel_launch(void* const* d_in, const int* in_sizes, int n_in,
                              void* d_out, int out_size, void* d_ws, size_t ws_size,
                              hipStream_t stream) {
  const float* emb  = (const float*)d_in[0];
  const float* Wq   = (const float*)d_in[1];
  const float* bq   = (const float*)d_in[2];
  const float* Wk   = (const float*)d_in[3];
  const float* bk   = (const float*)d_in[4];
  const float* Wv   = (const float*)d_in[5];
  const float* bv   = (const float*)d_in[6];
  const float* ln1w = (const float*)d_in[7];
  const float* ln1b = (const float*)d_in[8];
  const float* ln2w = (const float*)d_in[9];
  const float* ln2b = (const float*)d_in[10];
  const float* W1   = (const float*)d_in[11];
  const float* b1   = (const float*)d_in[12];
  const float* W2   = (const float*)d_in[13];
  const float* b2   = (const float*)d_in[14];
  float* out = (float*)d_out;

  char* p = (char*)d_ws;
  u16*   Wqkv_t = (u16*)p;   p += (size_t)3072 * 1024 * 2;
  u16*   W1t    = (u16*)p;   p += (size_t)4096 * 1024 * 2;
  u16*   W2t    = (u16*)p;   p += (size_t)1024 * 4096 * 2;
  float* x      = (float*)p; p += (size_t)4096 * 1024 * 4;
  u16*   xb     = (u16*)p;   p += (size_t)4096 * 1024 * 2;
  u16*   qkvb   = (u16*)p;   p += (size_t)3 * 32 * 2048 * 64 * 2;  // 25.2 MB
  float* ob     = (float*)p; p += (size_t)4096 * 1024 * 4;         // 16.8 MB
  float* y      = (float*)p; p += (size_t)4096 * 1024 * 4;
  u16*   yb     = (u16*)p;   p += (size_t)4096 * 1024 * 2;
  u16*   hb     = (u16*)qkvb; // alias: qkvb+ob (42 MB) dead before FFN1 writes hb (33.6 MB)
  u16*   vT     = (u16*)y;    // alias: vT (8.4 MB) dead before ln2 writes y
  float* part   = x;          // alias: x (16.8 MB fp32) dead before FFN2 z=1 partial
  if (ws_size < (size_t)(p - (char*)d_ws)) return;

  // fused: all weight transposes (2816 blocks) + ln1 (4096 blocks)
  prep_k<<<dim3(2816 + 4096), 256, 0, stream>>>(
      W1, W2, Wq, Wk, Wv, W1t, W2t, Wqkv_t, emb, ln1w, ln1b, x, xb);

  qkv_gemm<<<dim3(32, 24, 1), 256, 0, stream>>>(
      xb, Wqkv_t, 1024, 1024, 1024, bq, bk, bv, qkvb);

  vtrans_k<<<dim3(32, 32), 256, 0, stream>>>(qkvb + (size_t)64 * 2048 * 64, vT);

  attn_k<<<dim3(16, 32), 512, 0, stream>>>(qkvb, vT, ob);

  ln_k<<<dim3(4096), 256, 0, stream>>>(x, ob, ln2w, ln2b, y, yb);

  ffn1_gemm<<<dim3(32, 32, 1), 256, 0, stream>>>(
      yb, W1t, 1024, 1024, 1024, b1, 4096, hb);

  // FFN2 split-K=2: z=0 -> out (+b2+y), z=1 -> raw partial into `part`
  ffn2_gemm<<<dim3(32, 8, 2), 256, 0, stream>>>(
      hb, W2t, 2048, 4096, 4096, b2, y, 1024, out, part);

  reduce_k<<<dim3(4096), 256, 0, stream>>>(out, part);
}

// Round 12
// 321.811 us; speedup vs baseline: 1.0376x; 1.0072x over previous
//
#include <hip/hip_runtime.h>

// TransformerLayer on MI355X (gfx950), bf16 MFMA pipeline, fp32 LN/softmax/accum.
// R18 = R17 (324.1us verified) + vtrans fusion: qkv_gemm's epilogue writes V
// DIRECTLY in transposed [bh][dh][s] layout (4 consecutive-ss values per lane
// pack into one aligned 8B uint2 store -> same 32B-segment coalescing as the
// old scalar path, 4x fewer stores), eliminating the vtrans_k copy pass
// (16.8 MB traffic + one launch). Q/K paths and all other kernels unchanged.
// - GEMMs: 128x128/BK=64 2-phase LDS dbuf, 2 blocks/CU (structure ceiling
//   ~625TF; escapes closed: R7 splitK4, R9-R11 8-phase x3, R13 256-tile).
// - attn: R5-lineage flash attn (R14 setprio/defer-max net-negative here).

typedef unsigned short u16;
typedef unsigned int   u32;
typedef __bf16 bf16x8 __attribute__((ext_vector_type(8)));
typedef float  f32x4  __attribute__((ext_vector_type(4)));

#define NEG_INF (-__builtin_inff())

#if __has_builtin(__builtin_amdgcn_exp2f)
#define EXP2F(x) __builtin_amdgcn_exp2f(x)
#else
#define EXP2F(x) exp2f(x)
#endif

// pack: result = lo16:=a.hi16, hi16:=b.hi16 (trunc bf16 pair)
__device__ __forceinline__ u32 pack_bf16_trunc(float a, float b) {
#if __has_builtin(__builtin_amdgcn_perm)
  return __builtin_amdgcn_perm(__float_as_uint(b), __float_as_uint(a), 0x07060302u);
#else
  return (__float_as_uint(a) >> 16) | (__float_as_uint(b) & 0xFFFF0000u);
#endif
}

// fp32 -> bf16 RNE (finite inputs only)
__device__ __forceinline__ u16 f2b(float f) {
  u32 u = __float_as_uint(f);
  u = (u + 0x7fffu + ((u >> 16) & 1u)) >> 16;
  return (u16)u;
}

// async global->LDS, 16B per lane. LDS dest must be wave-uniform base + lane*16.
__device__ __forceinline__ void gload16(const void* g, void* l) {
  __builtin_amdgcn_global_load_lds(
      (const __attribute__((address_space(1))) u32*)g,
      (__attribute__((address_space(3))) u32*)l, 16, 0, 0);
}

__device__ __forceinline__ bf16x8 ld16(const u16* p) { return *(const bf16x8*)p; }

// ---------------------------------------------------------------------------
// LN body (verified ln_k), shared by prep_k (ln1) and ln_k (ln2).
__device__ __forceinline__
void ln_body(int row, const float* __restrict__ in, const float* __restrict__ in2,
             const float* __restrict__ w, const float* __restrict__ b,
             float* __restrict__ outf, u16* __restrict__ outb,
             float* rs, float* rq) {
  int t = threadIdx.x;
  const float4* ip = (const float4*)(in + (size_t)row * 1024);
  float4 x = ip[t];
  if (in2) {
    const float4* ip2 = (const float4*)(in2 + (size_t)row * 1024);
    float4 o = ip2[t];
    x.x += o.x; x.y += o.y; x.z += o.z; x.w += o.w;
  }
  float s = x.x + x.y + x.z + x.w;
  float q = x.x * x.x + x.y * x.y + x.z * x.z + x.w * x.w;
#pragma unroll
  for (int m = 32; m; m >>= 1) { s += __shfl_xor(s, m); q += __shfl_xor(q, m); }
  if ((t & 63) == 0) { rs[t >> 6] = s; rq[t >> 6] = q; }
  __syncthreads();
  s = rs[0] + rs[1] + rs[2] + rs[3];
  q = rq[0] + rq[1] + rq[2] + rq[3];
  float mean = s * (1.f / 1024.f);
  float var  = q * (1.f / 1024.f) - mean * mean;
  float rstd = rsqrtf(var + 1e-5f);
  float4 wv = ((const float4*)w)[t];
  float4 bv = ((const float4*)b)[t];
  float4 y;
  y.x = (x.x - mean) * rstd * wv.x + bv.x;
  y.y = (x.y - mean) * rstd * wv.y + bv.y;
  y.z = (x.z - mean) * rstd * wv.z + bv.z;
  y.w = (x.w - mean) * rstd * wv.w + bv.w;
  if (outf) ((float4*)(outf + (size_t)row * 1024))[t] = y;
  ushort4 ub;
  ub.x = f2b(y.x); ub.y = f2b(y.y); ub.z = f2b(y.z); ub.w = f2b(y.w);
  ((ushort4*)(outb + (size_t)row * 1024))[t] = ub;
}

// ---------------------------------------------------------------------------
// prep_k: ALL weight transposes (fp32->bf16, [R][C]->[C][R]) + ln1 in ONE
// launch. id < 2816: transpose work (W1 | W2 | Wq/Wk/Wv); id >= 2816: ln1 row.
__global__ __launch_bounds__(256)
void prep_k(const float* __restrict__ W1, const float* __restrict__ W2,
            const float* __restrict__ Wq, const float* __restrict__ Wk,
            const float* __restrict__ Wv,
            u16* __restrict__ W1t, u16* __restrict__ W2t,
            u16* __restrict__ Wqkv_t,
            const float* __restrict__ emb, const float* __restrict__ ln1w,
            const float* __restrict__ ln1b,
            float* __restrict__ x, u16* __restrict__ xb) {
  __shared__ float tile[64][65];   // transpose path (16.6 KB)
  __shared__ float rs[4], rq[4];   // ln path
  int id = blockIdx.x;
  if (id >= 2816) {                // ----- ln1 path -----
    ln_body(id - 2816, emb, nullptr, ln1w, ln1b, x, xb, rs, rq);
    return;
  }
  // ----- transpose path (verified transpose_all_k body) -----
  const float* in; u16* out; int R, C, r0, c0;
  if (id < 1024) {
    in = W1; out = W1t; R = 1024; C = 4096;
    r0 = (id & 15) * 64; c0 = (id >> 4) * 64;
  } else if (id < 2048) {
    id -= 1024;
    in = W2; out = W2t; R = 4096; C = 1024;
    r0 = (id >> 4) * 64; c0 = (id & 15) * 64;
  } else {
    id -= 2048;                    // 0..767: 48 head-matrices x 16 row-chunks
    int z = id >> 4, which = z >> 4, sub = z & 15;
    const float* base = which == 0 ? Wq : (which == 1 ? Wk : Wv);
    in = base + (size_t)sub * 1024 * 64;
    out = Wqkv_t + (size_t)which * 1024 * 1024 + (size_t)sub * 64 * 1024;
    R = 1024; C = 64;
    r0 = (id & 15) * 64; c0 = 0;
  }
  int tr = threadIdx.x >> 6, tc = threadIdx.x & 63;
#pragma unroll
  for (int i = 0; i < 16; i++) {
    int r = i * 4 + tr;
    tile[r][tc] = in[(size_t)(r0 + r) * C + c0 + tc];
  }
  __syncthreads();
#pragma unroll
  for (int i = 0; i < 16; i++) {
    int c = i * 4 + tr;
    out[(size_t)(c0 + c) * R + r0 + tc] = f2b(tile[tc][c]);
  }
}

// ---------------------------------------------------------------------------
// ln_k: standalone LN (used for ln2 = LN(x + ob)).
__global__ __launch_bounds__(256)
void ln_k(const float* __restrict__ in, const float* __restrict__ in2,
          const float* __restrict__ w, const float* __restrict__ b,
          float* __restrict__ outf, u16* __restrict__ outb) {
  __shared__ float rs[4], rq[4];
  ln_body(blockIdx.x, in, in2, w, b, outf, outb, rs, rq);
}

// ---------------------------------------------------------------------------
// 128x128 tile bf16 GEMM body, BK=64, 256 threads (4 waves, 2x2 of 64x64).
// XOR chunk swizzle -> conflict-free ds_read_b128. blockIdx.z = split-K slice.
// 2-phase LDS dbuf: stage k+1 BEFORE compute k, ONE barrier per K-step so the
// vmcnt(0) drain lands after the MFMA cluster (latency hidden). [R8, verified]
#define EPI_QKV  0
#define EPI_RELU 1
#define EPI_RES  2

// 0.125 * log2(e): folds the 1/sqrt(64) score scale AND the exp->exp2
// conversion into the Q projection (attention uses exp2 directly).
#define QSCALE 0.18033688011112042f

template <int EPI>
__device__ __forceinline__
void gemm_body(const u16* __restrict__ A, const u16* __restrict__ Bt,
               int K, int lda, int ldbt,
               const float* __restrict__ bias0, const float* __restrict__ bias1,
               const float* __restrict__ bias2, const float* __restrict__ res,
               int ldout, u16* __restrict__ outb, u16* __restrict__ vtout,
               float* __restrict__ outf, float* __restrict__ outp) {
  __shared__ __align__(16) u16 As[2][128 * 64];
  __shared__ __align__(16) u16 Bs[2][128 * 64];
  int t = threadIdx.x;
  int wave = t >> 6, lane = t & 63, quad = lane >> 4, l16 = lane & 15;
  int x7 = l16 & 7;
  int wm = (wave >> 1) * 64, wn = (wave & 1) * 64;
  int bm = blockIdx.x * 128, bn = blockIdx.y * 128;
  int zoff = blockIdx.z * K;

  const u16* Agl[4];
  const u16* Bgl[4];
#pragma unroll
  for (int i = 0; i < 4; i++) {
    int idx = i * 256 + t, r = idx >> 3, c = (idx & 7) ^ (r & 7);
    Agl[i] = A + (size_t)(bm + r) * lda + zoff + c * 8;
    Bgl[i] = Bt + (size_t)(bn + r) * ldbt + zoff + c * 8;
  }

  f32x4 acc[4][4] = {};

  // prologue: stage tile 0 into buffer 0
#pragma unroll
  for (int i = 0; i < 4; i++) {
    gload16(Agl[i], (u16*)As[0] + t * 8 + i * 2048);
    gload16(Bgl[i], (u16*)Bs[0] + t * 8 + i * 2048);
  }
  __syncthreads();

  int nk = K >> 6;
  for (int kt = 0; kt < nk; kt++) {
    const u16* Ac = As[kt & 1];
    const u16* Bc = Bs[kt & 1];
    if (kt + 1 < nk) {
      int k1 = (kt + 1) << 6;
      u16* An = (u16*)As[(kt + 1) & 1] + t * 8;
      u16* Bn = (u16*)Bs[(kt + 1) & 1] + t * 8;
#pragma unroll
      for (int i = 0; i < 4; i++) {
        gload16(Agl[i] + k1, An + i * 2048);
        gload16(Bgl[i] + k1, Bn + i * 2048);
      }
    }
#pragma unroll
    for (int kc = 0; kc < 2; kc++) {
      bf16x8 af[4], bfr[4];
#pragma unroll
      for (int i = 0; i < 4; i++) {
        int r = wm + i * 16 + l16;
        af[i] = *(const bf16x8*)(Ac + r * 64 + (((kc * 4 + quad) ^ x7) * 8));
      }
#pragma unroll
      for (int j = 0; j < 4; j++) {
        int r = wn + j * 16 + l16;
        bfr[j] = *(const bf16x8*)(Bc + r * 64 + (((kc * 4 + quad) ^ x7) * 8));
      }
#pragma unroll
      for (int i = 0; i < 4; i++)
#pragma unroll
        for (int j = 0; j < 4; j++)
          acc[i][j] = __builtin_amdgcn_mfma_f32_16x16x32_bf16(af[i], bfr[j],
                                                              acc[i][j], 0, 0, 0);
    }
    // one barrier per K-step: waits (a) all waves done reading cur buffer,
    // (b) vmcnt(0) drain of next-tile global_load_lds -- after the MFMAs.
    __syncthreads();
  }

#pragma unroll
  for (int i = 0; i < 4; i++) {
#pragma unroll
    for (int j = 0; j < 4; j++) {
      int c = bn + wn + j * 16 + l16;
      if (EPI == EPI_QKV) {
        int which = c >> 10, h = (c >> 6) & 15, d = c & 63;
        const float* bp = which == 0 ? bias0 : (which == 1 ? bias1 : bias2);
        float bias = bp[h * 64 + d];
        int r0 = bm + wm + i * 16 + quad * 4;          // rr=0..3 consecutive,
        int bb = r0 >> 11, ss = r0 & 2047;             // 4-aligned: same bb
        u16 w4[4];
#pragma unroll
        for (int rr = 0; rr < 4; rr++) {
          float v = acc[i][j][rr] + bias;
          if (which == 0) v *= QSCALE;  // prescale Q for base-2 softmax
          w4[rr] = f2b(v);
        }
        if (which == 2) {
          // V: write directly transposed into vT [bh][64][2048]; the 4
          // consecutive-ss values are contiguous -> one aligned 8B store.
          u32 lo = (u32)w4[0] | ((u32)w4[1] << 16);
          u32 hi = (u32)w4[2] | ((u32)w4[3] << 16);
          *(uint2*)(vtout + ((size_t)(bb * 16 + h) * 64 + d) * 2048 + ss) =
              make_uint2(lo, hi);
        } else {
#pragma unroll
          for (int rr = 0; rr < 4; rr++)
            outb[((size_t)(which * 32 + bb * 16 + h) * 2048 + ss + rr) * 64 + d] = w4[rr];
        }
      } else {
#pragma unroll
        for (int rr = 0; rr < 4; rr++) {
          int r = bm + wm + i * 16 + quad * 4 + rr;
          float v = acc[i][j][rr];
          if (EPI == EPI_RELU) {
            v += bias0[c];
            v = v > 0.f ? v : 0.f;
            outb[(size_t)r * ldout + c] = f2b(v);
          } else {
            if (blockIdx.z == 0) {
              v += bias0[c] + res[(size_t)r * ldout + c];
              outf[(size_t)r * ldout + c] = v;
            } else {
              outp[(size_t)r * ldout + c] = v;
            }
          }
        }
      }
    }
  }
}

__global__ __launch_bounds__(256)
void qkv_gemm(const u16* A, const u16* Bt, int K, int lda, int ldbt,
              const float* b0, const float* b1, const float* b2,
              u16* outb, u16* vtout) {
  gemm_body<EPI_QKV>(A, Bt, K, lda, ldbt, b0, b1, b2, nullptr, 0, outb, vtout,
                     nullptr, nullptr);
}
__global__ __launch_bounds__(256)
void ffn1_gemm(const u16* A, const u16* Bt, int K, int lda, int ldbt,
               const float* b0, int ldout, u16* outb) {
  gemm_body<EPI_RELU>(A, Bt, K, lda, ldbt, b0, nullptr, nullptr, nullptr, ldout,
                      outb, nullptr, nullptr, nullptr);
}
__global__ __launch_bounds__(256)
void ffn2_gemm(const u16* A, const u16* Bt, int K, int lda, int ldbt,
               const float* b0, const float* res, int ldout,
               float* outf, float* outp) {
  gemm_body<EPI_RES>(A, Bt, K, lda, ldbt, b0, nullptr, nullptr, res, ldout,
                     nullptr, nullptr, outf, outp);
}

// out[i] += part[i]  (fp32, float4)
__global__ __launch_bounds__(256)
void reduce_k(float* __restrict__ out, const float* __restrict__ part) {
  int i = blockIdx.x * 256 + threadIdx.x;
  float4 a = ((const float4*)part)[i];
  float4 b = ((float4*)out)[i];
  b.x += a.x; b.y += a.y; b.z += a.z; b.w += a.w;
  ((float4*)out)[i] = b;
}

// ---------------------------------------------------------------------------
// Flash attention v5, causal. Grid (16, 32), 512 threads (8 waves).
// LDS-staged K/V dbuf, 1 barrier/iter, S^T orientation, 2-shuffle softmax rows,
// raw v_exp_f32, v_perm P-pack, alpha broadcast via per-wave LDS aux. [verified]
__global__ __launch_bounds__(512, 6)
void attn_k(const u16* __restrict__ qkv, const u16* __restrict__ vt,
            float* __restrict__ o) {
  int bh = blockIdx.y, b = bh >> 4, h = bh & 15;
  int Qt = b ? (15 - (int)blockIdx.x) : (int)blockIdx.x;  // causal balance
  int t = threadIdx.x;
  int wave = t >> 6, lane = t & 63, quad = lane >> 4, l16 = lane & 15;
  int x7 = l16 & 7;
  int q0 = Qt * 128 + wave * 16;

  const u16* qg = qkv + (size_t)bh * (2048 * 64);
  const u16* kg = qkv + (size_t)(32 + bh) * (2048 * 64);
  const u16* vg = vt + (size_t)bh * (64 * 2048);  // [dh][s]

  __shared__ __align__(16) u16 Ks[2][64 * 64];
  __shared__ __align__(16) u16 Vs[2][64 * 64];
  __shared__ __align__(16) u16 Ps[8][16 * 64 + 32];  // +64B aux per wave
  u16* Pw = Ps[wave];
  float* auxf = (float*)(Pw + 1024);

  int sr = t >> 3, sc_ = (t & 7) ^ (sr & 7);

  gload16(kg + (size_t)sr * 64 + sc_ * 8, Ks[0] + t * 8);
  gload16(vg + (size_t)sr * 2048 + sc_ * 8, Vs[0] + t * 8);

  bf16x8 qf0 = ld16(qg + (size_t)(q0 + l16) * 64 + quad * 8);
  bf16x8 qf1 = ld16(qg + (size_t)(q0 + l16) * 64 + 32 + quad * 8);

  f32x4 oacc[4] = {};
  float mo = NEG_INF, ll = 0.f;
  int kmax_w = q0 >> 6;
  int klast = 2 * Qt + 1;

  __syncthreads();

  for (int kt = 0; kt <= klast; kt++) {
    const u16* ks = Ks[kt & 1];
    const u16* vs = Vs[kt & 1];
    if (kt < klast) {
      gload16(kg + (size_t)((kt + 1) * 64 + sr) * 64 + sc_ * 8, Ks[(kt + 1) & 1] + t * 8);
      gload16(vg + (size_t)sr * 2048 + (kt + 1) * 64 + sc_ * 8, Vs[(kt + 1) & 1] + t * 8);
    }
    if (kt <= kmax_w) {
      // ---- S^T: A = K rows (m = kv), B = Q rows (n = q) ----
      f32x4 sc[4];
#pragma unroll
      for (int g = 0; g < 4; g++) {
        const u16* kr = ks + (g * 16 + l16) * 64;
        bf16x8 kf0 = *(const bf16x8*)(kr + ((quad ^ x7) * 8));
        bf16x8 kf1 = *(const bf16x8*)(kr + (((4 + quad) ^ x7) * 8));
        f32x4 s = {};
        s = __builtin_amdgcn_mfma_f32_16x16x32_bf16(kf0, qf0, s, 0, 0, 0);
        s = __builtin_amdgcn_mfma_f32_16x16x32_bf16(kf1, qf1, s, 0, 0, 0);
        sc[g] = s;
      }

      if (kt == kmax_w) {  // diagonal tile: mask kv > q
#pragma unroll
        for (int g = 0; g < 4; g++) {
          int kvb = kt * 64 + g * 16 + quad * 4;
#pragma unroll
          for (int rr = 0; rr < 4; rr++)
            if (kvb + rr > q0 + l16) sc[g][rr] = NEG_INF;
        }
      }

      // ---- online softmax, row = q = l16 ----
      float mx = sc[0][0];
#pragma unroll
      for (int g = 0; g < 4; g++)
#pragma unroll
        for (int rr = 0; rr < 4; rr++) mx = fmaxf(mx, sc[g][rr]);
      mx = fmaxf(mx, __shfl_xor(mx, 16));
      mx = fmaxf(mx, __shfl_xor(mx, 32));
      float mnew = fmaxf(mo, mx);
      float al = EXP2F(mo - mnew);
      mo = mnew;

      float sum = 0.f;
#pragma unroll
      for (int g = 0; g < 4; g++) {
        float p0 = EXP2F(sc[g][0] - mnew);
        float p1 = EXP2F(sc[g][1] - mnew);
        float p2 = EXP2F(sc[g][2] - mnew);
        float p3 = EXP2F(sc[g][3] - mnew);
        sum += (p0 + p1) + (p2 + p3);
        u32 lo = pack_bf16_trunc(p0, p1);
        u32 hi = pack_bf16_trunc(p2, p3);
        int slot = (2 * g + (quad >> 1)) ^ x7;
        *(uint2*)(Pw + l16 * 64 + slot * 8 + (quad & 1) * 4) = make_uint2(lo, hi);
      }
      sum += __shfl_xor(sum, 16);
      sum += __shfl_xor(sum, 32);
      ll = ll * al + sum;

      // rescale O: alpha indexed by q=l16 -> broadcast via per-wave LDS aux
      if (lane < 16) auxf[lane] = al;
      f32x4 av = *(const f32x4*)(auxf + quad * 4);
#pragma unroll
      for (int g = 0; g < 4; g++)
#pragma unroll
        for (int rr = 0; rr < 4; rr++) oacc[g][rr] *= av[rr];

      // ---- O += P(A) x V^T(B) ----
      bf16x8 pf0 = *(const bf16x8*)(Pw + l16 * 64 + ((quad ^ x7) * 8));
      bf16x8 pf1 = *(const bf16x8*)(Pw + l16 * 64 + (((4 + quad) ^ x7) * 8));
#pragma unroll
      for (int g = 0; g < 4; g++) {
        const u16* vr = vs + (g * 16 + l16) * 64;
        bf16x8 vf0 = *(const bf16x8*)(vr + ((quad ^ x7) * 8));
        bf16x8 vf1 = *(const bf16x8*)(vr + (((4 + quad) ^ x7) * 8));
        oacc[g] = __builtin_amdgcn_mfma_f32_16x16x32_bf16(pf0, vf0, oacc[g], 0, 0, 0);
        oacc[g] = __builtin_amdgcn_mfma_f32_16x16x32_bf16(pf1, vf1, oacc[g], 0, 0, 0);
      }
    }
    __syncthreads();
  }

  // epilogue: O row = m = quad*4+rr, col = dh = g*16+l16; l indexed by l16
  if (lane < 16) auxf[lane] = ll;
  f32x4 lv = *(const f32x4*)(auxf + quad * 4);
  float rinv[4];
#pragma unroll
  for (int rr = 0; rr < 4; rr++) rinv[rr] = 1.f / lv[rr];
  float* op = o + ((size_t)b * 2048 + q0) * 1024 + h * 64;
#pragma unroll
  for (int g = 0; g < 4; g++)
#pragma unroll
    for (int rr = 0; rr < 4; rr++)
      op[(size_t)(quad * 4 + rr) * 1024 + g * 16 + l16] = oacc[g][rr] * rinv[rr];
}

// ---------------------------------------------------------------------------
extern "C" void kernel_launch(void* const* d_in, const int* in_sizes, int n_in,
                              void* d_out, int out_size, void* d_ws, size_t ws_size,
                              hipStream_t stream) {
  const float* emb  = (const float*)d_in[0];
  const float* Wq   = (const float*)d_in[1];
  const float* bq   = (const float*)d_in[2];
  const float* Wk   = (const float*)d_in[3];
  const float* bk   = (const float*)d_in[4];
  const float* Wv   = (const float*)d_in[5];
  const float* bv   = (const float*)d_in[6];
  const float* ln1w = (const float*)d_in[7];
  const float* ln1b = (const float*)d_in[8];
  const float* ln2w = (const float*)d_in[9];
  const float* ln2b = (const float*)d_in[10];
  const float* W1   = (const float*)d_in[11];
  const float* b1   = (const float*)d_in[12];
  const float* W2   = (const float*)d_in[13];
  const float* b2   = (const float*)d_in[14];
  float* out = (float*)d_out;

  char* p = (char*)d_ws;
  u16*   Wqkv_t = (u16*)p;   p += (size_t)3072 * 1024 * 2;
  u16*   W1t    = (u16*)p;   p += (size_t)4096 * 1024 * 2;
  u16*   W2t    = (u16*)p;   p += (size_t)1024 * 4096 * 2;
  float* x      = (float*)p; p += (size_t)4096 * 1024 * 4;
  u16*   xb     = (u16*)p;   p += (size_t)4096 * 1024 * 2;
  u16*   qkvb   = (u16*)p;   p += (size_t)3 * 32 * 2048 * 64 * 2;  // 25.2 MB
  float* ob     = (float*)p; p += (size_t)4096 * 1024 * 4;         // 16.8 MB
  float* y      = (float*)p; p += (size_t)4096 * 1024 * 4;
  u16*   yb     = (u16*)p;   p += (size_t)4096 * 1024 * 2;
  u16*   hb     = (u16*)qkvb; // alias: qkvb+ob (42 MB) dead before FFN1 writes hb (33.6 MB)
  u16*   vT     = (u16*)y;    // alias: vT (8.4 MB) dead before ln2 writes y
  float* part   = x;          // alias: x (16.8 MB fp32) dead before FFN2 z=1 partial
  if (ws_size < (size_t)(p - (char*)d_ws)) return;

  // fused: all weight transposes (2816 blocks) + ln1 (4096 blocks)
  prep_k<<<dim3(2816 + 4096), 256, 0, stream>>>(
      W1, W2, Wq, Wk, Wv, W1t, W2t, Wqkv_t, emb, ln1w, ln1b, x, xb);

  // QKV: V written directly transposed into vT (vtrans_k eliminated)
  qkv_gemm<<<dim3(32, 24, 1), 256, 0, stream>>>(
      xb, Wqkv_t, 1024, 1024, 1024, bq, bk, bv, qkvb, vT);

  attn_k<<<dim3(16, 32), 512, 0, stream>>>(qkvb, vT, ob);

  ln_k<<<dim3(4096), 256, 0, stream>>>(x, ob, ln2w, ln2b, y, yb);

  ffn1_gemm<<<dim3(32, 32, 1), 256, 0, stream>>>(
      yb, W1t, 1024, 1024, 1024, b1, 4096, hb);

  // FFN2 split-K=2: z=0 -> out (+b2+y), z=1 -> raw partial into `part`
  ffn2_gemm<<<dim3(32, 8, 2), 256, 0, stream>>>(
      hb, W2t, 2048, 4096, 4096, b2, y, 1024, out, part);

  reduce_k<<<dim3(4096), 256, 0, stream>>>(out, part);
}